// Round 3
// baseline (408.757 us; speedup 1.0000x reference)
//
#include <hip/hip_runtime.h>
#include <stdint.h>

typedef unsigned short u16;
typedef __attribute__((ext_vector_type(8))) short short8;
typedef __attribute__((ext_vector_type(4))) short s16x4;
typedef __attribute__((ext_vector_type(4))) float f32x4;
typedef __attribute__((ext_vector_type(16))) float f32x16;

__device__ __forceinline__ u16 f2bf(float f) {
  uint32_t x = __float_as_uint(f);
  x += 0x7fff + ((x >> 16) & 1);
  return (u16)(x >> 16);
}
__device__ __forceinline__ float bf2f(u16 u) {
  return __uint_as_float(((uint32_t)u) << 16);
}
__device__ __forceinline__ f32x4 mfma16(short8 a, short8 b, f32x4 c) {
  return __builtin_amdgcn_mfma_f32_16x16x32_bf16(a, b, c, 0, 0, 0);
}
__device__ __forceinline__ f32x16 mfma32(short8 a, short8 b, f32x16 c) {
  return __builtin_amdgcn_mfma_f32_32x32x16_bf16(a, b, c, 0, 0, 0);
}
__device__ __forceinline__ f32x4 mfma16k16(s16x4 a, s16x4 b, f32x4 c) {
  return __builtin_amdgcn_mfma_f32_16x16x16bf16_1k(a, b, c, 0, 0, 0);
}
__device__ __forceinline__ void gld16(const u16* g, u16* l) {
  __builtin_amdgcn_global_load_lds(
      (const __attribute__((address_space(1))) unsigned int*)g,
      (__attribute__((address_space(3))) unsigned int*)l, 16, 0, 0);
}
__device__ __forceinline__ float exp2a(float x) {  // raw v_exp_f32 (2^x)
  float r;
  asm("v_exp_f32 %0, %1" : "=v"(r) : "v"(x));
  return r;
}

#define WAIT_VM(n) asm volatile("s_waitcnt vmcnt(" #n ")" ::: "memory")

// ---------------- fused fp32 -> bf16 conversion (x | Wqkv | Wout) ----------------
__global__ __launch_bounds__(256) void cvt_all(const float* __restrict__ x,
                                               const float* __restrict__ wqkv,
                                               const float* __restrict__ wout,
                                               u16* __restrict__ xb,
                                               u16* __restrict__ wqkvb,
                                               u16* __restrict__ woutb) {
  long i = ((long)blockIdx.x * 256 + threadIdx.x) * 8;
  const float* s;
  u16* d;
  long off;
  if (i < 8388608) {
    s = x; d = xb; off = i;
  } else if (i < 20971520) {
    s = wqkv; d = wqkvb; off = i - 8388608;
  } else {
    s = wout; d = woutb; off = i - 20971520;
  }
  f32x4 a = *(const f32x4*)(s + off);
  f32x4 b = *(const f32x4*)(s + off + 4);
  short8 o;
#pragma unroll
  for (int j = 0; j < 4; j++) {
    o[j] = (short)f2bf(a[j]);
    o[j + 4] = (short)f2bf(b[j]);
  }
  *(short8*)(d + off) = o;
}

// ---------------- QKV GEMM: 256x256 tile, 8 waves, BK=32, 4-ring LDS ----------------
// C = A(4096x2048) * B(6144x2048)^T, bf16 BT layout. K = 2048 -> 64 K-tiles.
// FREE-RUN tile body (round-3 change): ONE barrier per tile, no mid-tile barriers.
// Round-2 measured full LDS/MFMA pipe serialization (2960 cyc/tile == reads+MFMA+
// barriers, serial): barrier-locked cohorts force all-wave read drain then all-wave
// MFMA. Fix: {STAGE(tau+3); 12 ds_read; 32 MFMA} in one barrier-free region -- the
// compiler's fine-grained lgkmcnt starts MFMAs after ~5 reads, and wave drift lets
// one wave's MFMAs overlap another's LDS service (m114). Ring safety needs only the
// end-of-tile barrier: all waves' reads of ring tau are lgkm-consumed before their
// MFMAs (which precede barrier tau); staging ring (tau+4)&3 == tau&3 is issued only
// after barrier tau releases. Counted vmcnt(8) at tile end (tiles tau+2, tau+3 stay
// in flight; drains 8->4->0 only at tau=60/61/62). Loop unrolled x4 -> ring bases
// are compile-time constants.
// LDS chunk swizzle (validated round-2, 0 bank conflicts): stored 16B chunk at row
// r, position p holds global chunk (p - (r>>1)) & 3; staging permutes the per-lane
// GLOBAL source chunk (LDS dest lane-contiguous as global_load_lds requires);
// fragment reads use position ((quad + (l15>>1)) & 3).
// Epilogue: q (scaled by 1/sqrt(128)*log2e) & k head-major [B,H,T,128] scatter;
//           v transposed per head [B,H,128,T] (8B stores along t).
__global__ __launch_bounds__(512, 2) void gemm_qkv(const u16* __restrict__ A,
                                                   const u16* __restrict__ Bw,
                                                   u16* __restrict__ q3) {
  __shared__ __align__(16) u16 SA[32768];  // 4 rings x [256 rows][32 k] bf16 = 64 KiB
  __shared__ __align__(16) u16 SB[32768];  // 64 KiB
  // bijective XCD swizzle (m204 form, nwg=384, q=48, r=0): each XCD owns 3 n-panels
  const int id = blockIdx.x;
  const int swz = (id & 7) * 48 + (id >> 3);
  const int by = swz & 15, bx = swz >> 4;
  const int m0 = by * 256, n0 = bx * 256;
  const int t = threadIdx.x, w = t >> 6, lane = t & 63;
  const int quad = lane >> 4, l15 = lane & 15;
  const int wm = w >> 2, wn = w & 3;  // 2 x 4 wave grid; per-wave C = 128 x 64
  // staging: thread t -> row rS = t>>2 (and rS+128), LDS position pS = t&3.
  // source chunk cS = (pS - (rS>>1)) & 3; rS+128 -> (rS>>1)+64 == same mod 4.
  const int rS = t >> 2, pS = t & 3;
  const int cS = (pS - (rS >> 1)) & 3;
  const size_t arow = (size_t)(m0 + rS) * 2048 + cS * 8;
  const size_t brow = (size_t)(n0 + rS) * 2048 + cS * 8;

  f32x4 acc[8][4] = {};
  // fragment-read swizzled chunk position: fragment row bases are multiples of 16
  // -> (row>>1)&3 == (l15>>1)&3 -> uniform per lane.
  const int pq = ((quad + (l15 >> 1)) & 3) * 8;

#define STAGE_PAIR(KT)                                                        \
  {                                                                           \
    const u16* ga_ = A + arow + (size_t)(KT) * 32;                            \
    u16* la_ = SA + ((KT) & 3) * 8192 + t * 8;                                \
    gld16(ga_, la_);                                                          \
    gld16(ga_ + (size_t)128 * 2048, la_ + 4096);                              \
    const u16* gb_ = Bw + brow + (size_t)(KT) * 32;                           \
    u16* lb_ = SB + ((KT) & 3) * 8192 + t * 8;                                \
    gld16(gb_, lb_);                                                          \
    gld16(gb_ + (size_t)128 * 2048, lb_ + 4096);                              \
  }

// One K-tile, free-run: stage -> 12 ds_read -> 32 MFMA -> counted wait -> barrier.
#define TILE(RING, TAU, DO_STAGE, WAIT)                                       \
  {                                                                           \
    const u16* Sa_ = SA + (RING) * 8192;                                      \
    const u16* Sb_ = SB + (RING) * 8192;                                      \
    if (DO_STAGE) STAGE_PAIR((TAU) + 3);                                      \
    short8 af[4], af2[4], bfr[4];                                             \
    _Pragma("unroll") for (int i = 0; i < 4; i++)                             \
        af[i] = *(const short8*)&Sa_[(wm * 128 + i * 16 + l15) * 32 + pq];    \
    _Pragma("unroll") for (int n = 0; n < 4; n++)                             \
        bfr[n] = *(const short8*)&Sb_[(wn * 64 + n * 16 + l15) * 32 + pq];    \
    _Pragma("unroll") for (int i = 0; i < 4; i++)                             \
        af2[i] = *(const short8*)&Sa_[(wm * 128 + 64 + i * 16 + l15) * 32 + pq]; \
    __builtin_amdgcn_s_setprio(1);                                            \
    _Pragma("unroll") for (int mi = 0; mi < 4; mi++)                          \
      _Pragma("unroll") for (int ni = 0; ni < 4; ni++)                        \
          acc[mi][ni] = mfma16(af[mi], bfr[ni], acc[mi][ni]);                 \
    _Pragma("unroll") for (int mi = 0; mi < 4; mi++)                          \
      _Pragma("unroll") for (int ni = 0; ni < 4; ni++)                        \
          acc[4 + mi][ni] = mfma16(af2[mi], bfr[ni], acc[4 + mi][ni]);        \
    __builtin_amdgcn_s_setprio(0);                                            \
    WAIT;                                                                     \
    __builtin_amdgcn_s_barrier();                                             \
  }

  // prologue: tiles 0,1,2 in flight (12 loads); wait for tile 0 (oldest 4)
  STAGE_PAIR(0);
  STAGE_PAIR(1);
  STAGE_PAIR(2);
  WAIT_VM(8);
  __builtin_amdgcn_s_barrier();

#pragma unroll 1
  for (int kt = 0; kt < 60; kt += 4) {
    TILE(0, kt + 0, true, WAIT_VM(8));
    TILE(1, kt + 1, true, WAIT_VM(8));
    TILE(2, kt + 2, true, WAIT_VM(8));
    TILE(3, kt + 3, true, WAIT_VM(8));
  }
  // peeled tail: tau 60 stages tile 63; then drain 8 -> 4 -> 0
  TILE(0, 60, true, WAIT_VM(8));
  TILE(1, 61, false, WAIT_VM(4));
  TILE(2, 62, false, WAIT_VM(0));
  TILE(3, 63, false, (void)0);
#undef TILE
#undef STAGE_PAIR

  // ---- epilogue: scatter into q | k | vT (layouts match rope_k / attn_k) ----
  // C row = m0 + wm*128 + mi*16 + quad*4 + r ; C col = n0 + wn*64 + ni*16 + l15
  const int which = n0 >> 11;  // 0=q 1=k 2=v (2048 % 256 == 0 -> block-uniform)
  const int bb = m0 >> 11, tt0 = m0 & 2047;
  if (which == 2) {
    u16* vbase = q3 + 16777216;
#pragma unroll
    for (int ni = 0; ni < 4; ni++) {
      const int gcol = (n0 & 2047) + wn * 64 + ni * 16 + l15;
      const int hh = gcol >> 7, di = gcol & 127;
      u16* vb = vbase + ((size_t)(bb * 16 + hh) * 128 + di) * 2048;
#pragma unroll
      for (int mi = 0; mi < 8; mi++) {
        const int tloc = tt0 + wm * 128 + mi * 16 + quad * 4;
        s16x4 st;
#pragma unroll
        for (int r = 0; r < 4; r++) st[r] = (short)f2bf(acc[mi][ni][r]);
        *(s16x4*)(vb + tloc) = st;  // 4 consecutive t -> 8B store
      }
    }
  } else {
    const float sc = (which == 0) ? 0.1275174f : 1.0f;  // 1/sqrt(128)*log2(e)
    u16* base = q3 + (size_t)which * 8388608;
#pragma unroll
    for (int ni = 0; ni < 4; ni++) {
      const int gcol = (n0 & 2047) + wn * 64 + ni * 16 + l15;
      const int hh = gcol >> 7, di = gcol & 127;
      u16* qb = base + ((size_t)(bb * 16 + hh) * 2048) * 128 + di;
#pragma unroll
      for (int mi = 0; mi < 8; mi++) {
        const int tloc = tt0 + wm * 128 + mi * 16 + quad * 4;
#pragma unroll
        for (int r = 0; r < 4; r++)
          qb[(size_t)(tloc + r) * 128] = f2bf(acc[mi][ni][r] * sc);
      }
    }
  }
}

// ---------------- BT GEMM (kept for the output projection), 32x32x16 MFMA --------
template <int EPI>
__global__ __launch_bounds__(256) void gemm_bt(const u16* __restrict__ A,
                                               const u16* __restrict__ B,
                                               int K, void* __restrict__ Cv, int N) {
  __shared__ __align__(16) u16 SMEM[8448];  // staging 16KB; EPI=1 epilogue f32[32][132]
  u16* As = SMEM;
  u16* Bs = SMEM + 4096;
  const int m0 = blockIdx.y * 128, n0 = blockIdx.x * 128;
  const int t = threadIdx.x, w = t >> 6, lane = t & 63;
  const int l31 = lane & 31, half = lane >> 5;
  const int rb = (w >> 1) * 64, cb = (w & 1) * 64;
  f32x16 acc[2][2] = {};
  const int rowS = w * 16 + (lane >> 2);                // staged row (0..63, +64 second)
  const int cS = ((lane & 3) - (rowS >> 1)) & 3;        // swizzled source chunk
  const u16* ag = A + (size_t)(m0 + rowS) * K + cS * 8;
  const u16* bg = B + (size_t)(n0 + rowS) * K + cS * 8;
  u16* al = As + w * 512 + lane * 8;  // lane-contiguous: base + lane*16B
  u16* bl = Bs + w * 512 + lane * 8;
  const size_t rowskip = (size_t)64 * K;
  const int p0 = ((0 * 2 + half + (l31 >> 1)) & 3) * 8;  // kh=0
  const int p1 = ((1 * 2 + half + (l31 >> 1)) & 3) * 8;  // kh=1
  for (int k0 = 0; k0 < K; k0 += 32) {
    __syncthreads();
    gld16(ag, al);
    gld16(ag + rowskip, al + 2048);
    gld16(bg, bl);
    gld16(bg + rowskip, bl + 2048);
    ag += 32;
    bg += 32;
    __syncthreads();
    short8 af[2][2], bfr[2][2];
#pragma unroll
    for (int mi = 0; mi < 2; mi++) {
      af[mi][0] = *(const short8*)&As[(rb + mi * 32 + l31) * 32 + p0];
      af[mi][1] = *(const short8*)&As[(rb + mi * 32 + l31) * 32 + p1];
    }
#pragma unroll
    for (int ni = 0; ni < 2; ni++) {
      bfr[ni][0] = *(const short8*)&Bs[(cb + ni * 32 + l31) * 32 + p0];
      bfr[ni][1] = *(const short8*)&Bs[(cb + ni * 32 + l31) * 32 + p1];
    }
#pragma unroll
    for (int kh = 0; kh < 2; kh++)
#pragma unroll
      for (int mi = 0; mi < 2; mi++)
#pragma unroll
        for (int ni = 0; ni < 2; ni++)
          acc[mi][ni] = mfma32(af[mi][kh], bfr[ni][kh], acc[mi][ni]);
  }

  if (EPI == 0) {
    const int which = n0 >> 11;
    const int hh = (n0 & 2047) >> 7;
    const int bb = m0 >> 11, tt0 = m0 & 2047;
    u16* q3 = (u16*)Cv;
    if (which == 2) {
      u16* vbase = q3 + 16777216 + ((size_t)(bb * 16 + hh) * 128) * 2048;
#pragma unroll
      for (int mi = 0; mi < 2; mi++)
#pragma unroll
        for (int ni = 0; ni < 2; ni++) {
          int di = cb + ni * 32 + l31;
          int trow = tt0 + rb + mi * 32 + half * 4;
#pragma unroll
          for (int rg2 = 0; rg2 < 4; rg2++) {
            s16x4 st;
#pragma unroll
            for (int j = 0; j < 4; j++) st[j] = (short)f2bf(acc[mi][ni][rg2 * 4 + j]);
            *(s16x4*)(vbase + (size_t)di * 2048 + trow + rg2 * 8) = st;
          }
        }
    } else {
      const float sc = (which == 0) ? 0.1275174f : 1.0f;
      u16* base = q3 + (size_t)which * 8388608 + ((size_t)(bb * 16 + hh) * 2048) * 128;
#pragma unroll
      for (int mi = 0; mi < 2; mi++)
#pragma unroll
        for (int ni = 0; ni < 2; ni++) {
          int di = cb + ni * 32 + l31;
          int trow = tt0 + rb + mi * 32 + half * 4;
#pragma unroll
          for (int reg = 0; reg < 16; reg++) {
            int tt = trow + (reg & 3) + 8 * (reg >> 2);
            base[(size_t)tt * 128 + di] = f2bf(acc[mi][ni][reg] * sc);
          }
        }
    }
  } else {
    float* Es = (float*)SMEM;  // [32][132]
    float* C = (float*)Cv;
#pragma unroll
    for (int r = 0; r < 4; r++) {
      __syncthreads();
      if ((w >> 1) == (r >> 1)) {
        const int mi = r & 1;
#pragma unroll
        for (int ni = 0; ni < 2; ni++) {
          int col = cb + ni * 32 + l31;
#pragma unroll
          for (int reg = 0; reg < 16; reg++) {
            int lrow = (reg & 3) + 8 * (reg >> 2) + half * 4;
            Es[lrow * 132 + col] = acc[mi][ni][reg];
          }
        }
      }
      __syncthreads();
#pragma unroll
      for (int it = 0; it < 4; it++) {
        int idx = it * 256 + t;
        int row = idx >> 5, ch = idx & 31;
        f32x4 vv = *(const f32x4*)&Es[row * 132 + ch * 4];
        *(f32x4*)&C[(size_t)(m0 + r * 32 + row) * N + n0 + ch * 4] = vv;
      }
    }
  }
}

// ---------------- RoPE in-place on q,k (heads 0..7 only) ----------------
__global__ __launch_bounds__(256) void rope_k(u16* __restrict__ q, u16* __restrict__ k,
                                              const float* __restrict__ cosT,
                                              const float* __restrict__ sinT) {
  int t = threadIdx.x;
  int row = blockIdx.x * 4 + (t >> 6);  // over (b, h<8, tpos)
  int i = t & 63;
  int b = row >> 14;
  int h = (row >> 11) & 7;
  int tp = row & 2047;
  size_t base = ((size_t)((b * 16 + h) * 2048 + tp)) * 128 + 2 * i;
  float c = cosT[tp * 64 + i], s = sinT[tp * 64 + i];
  {
    uint32_t u = *(uint32_t*)(q + base);
    float x0 = bf2f((u16)(u & 0xffff)), x1 = bf2f((u16)(u >> 16));
    float re = x0 * c - x1 * s, im = x0 * s + x1 * c;
    *(uint32_t*)(q + base) = (uint32_t)f2bf(re) | ((uint32_t)f2bf(im) << 16);
  }
  {
    uint32_t u = *(uint32_t*)(k + base);
    float x0 = bf2f((u16)(u & 0xffff)), x1 = bf2f((u16)(u >> 16));
    float re = x0 * c - x1 * s, im = x0 * s + x1 * c;
    *(uint32_t*)(k + base) = (uint32_t)f2bf(re) | ((uint32_t)f2bf(im) << 16);
  }
}

// ---------------- flash attention, S^T orientation ----------------
__global__ __launch_bounds__(256, 2) void attn_k(const u16* __restrict__ qh,
                                                 const u16* __restrict__ kh,
                                                 const u16* __restrict__ vTh,
                                                 u16* __restrict__ attno) {
  __shared__ __align__(16) u16 Ks[8192];  // 64 keys x 128 d, XOR-swizzled 16B chunks
  __shared__ __align__(16) u16 Vt[8192];  // 128 d x 64 keys, XOR-swizzled 16B chunks
  const int i = blockIdx.x;
  const int jj = i & 255, half = i >> 8;
  const int bh = jj >> 3, t8 = jj & 7;
  const int qt = half ? (15 - t8) : t8;
  const int q0 = qt * 128;
  const int t = threadIdx.x, w = t >> 6, lane = t & 63;
  const int quad = lane >> 4, l15 = lane & 15;
  const size_t bhoff = (size_t)bh * 262144;

  short8 qb[2][4];
  {
    const u16* qp = qh + bhoff + (size_t)(q0 + w * 32 + l15) * 128 + quad * 8;
#pragma unroll
    for (int qq = 0; qq < 2; qq++)
#pragma unroll
      for (int ks = 0; ks < 4; ks++)
        qb[qq][ks] = *(const short8*)(qp + qq * 2048 + ks * 32);
  }
  f32x4 of[2][8] = {};
  float mst[2] = {-1e30f, -1e30f}, lst[2] = {0.f, 0.f};
  const int nkt = 2 * qt + 2;
  const int wq0 = q0 + w * 32;

  for (int kt = 0; kt < nkt; kt++) {
    const int k0 = kt * 64;
    __syncthreads();
    {
#pragma unroll
      for (int it = 0; it < 4; it++) {  // K: 64 rows x 16 chunks
        int L = it * 256 + t;
        int key = L >> 4, c = L & 15;
        gld16(kh + bhoff + (size_t)(k0 + key) * 128 + ((c ^ (key & 15)) * 8),
              Ks + (size_t)L * 8);
      }
#pragma unroll
      for (int it = 0; it < 4; it++) {  // V^T: 128 rows x 8 chunks
        int L = it * 256 + t;
        int d = L >> 3, c = L & 7;
        gld16(vTh + bhoff + (size_t)d * 2048 + k0 + ((c ^ (d & 7)) * 8),
              Vt + (size_t)L * 8);
      }
    }
    __syncthreads();
    if (k0 <= wq0 + 31) {
      f32x4 sacc[2][4];
#pragma unroll
      for (int qq = 0; qq < 2; qq++)
#pragma unroll
        for (int kk = 0; kk < 4; kk++) sacc[qq][kk] = (f32x4){0.f, 0.f, 0.f, 0.f};
#pragma unroll
      for (int kk = 0; kk < 4; kk++) {
        short8 kf[4];
#pragma unroll
        for (int ks = 0; ks < 4; ks++)
          kf[ks] = *(const short8*)&Ks[(kk * 16 + l15) * 128 + ((ks * 4 + quad) ^ l15) * 8];
#pragma unroll
        for (int qq = 0; qq < 2; qq++)
#pragma unroll
          for (int ks = 0; ks < 4; ks++)
            sacc[qq][kk] = mfma16(kf[ks], qb[qq][ks], sacc[qq][kk]);
      }
      const bool needmask = (k0 + 63 > wq0);
      s16x4 pf[2][4];
      float alpha[2];
#pragma unroll
      for (int qq = 0; qq < 2; qq++) {
        const int qg = wq0 + qq * 16 + l15;
        if (needmask) {
#pragma unroll
          for (int kk = 0; kk < 4; kk++)
#pragma unroll
            for (int rg = 0; rg < 4; rg++)
              if (k0 + kk * 16 + quad * 4 + rg > qg) sacc[qq][kk][rg] = -1e30f;
        }
        float pm = -1e30f;
#pragma unroll
        for (int kk = 0; kk < 4; kk++)
#pragma unroll
          for (int rg = 0; rg < 4; rg++) pm = fmaxf(pm, sacc[qq][kk][rg]);
        pm = fmaxf(pm, __shfl_xor(pm, 16));
        pm = fmaxf(pm, __shfl_xor(pm, 32));
        float mnew = fmaxf(mst[qq], pm);
        alpha[qq] = exp2a(mst[qq] - mnew);
        mst[qq] = mnew;
        float ps = 0.f;
#pragma unroll
        for (int kk = 0; kk < 4; kk++) {
          float e0 = exp2a(sacc[qq][kk][0] - mnew);
          float e1 = exp2a(sacc[qq][kk][1] - mnew);
          float e2 = exp2a(sacc[qq][kk][2] - mnew);
          float e3 = exp2a(sacc[qq][kk][3] - mnew);
          ps += (e0 + e1) + (e2 + e3);
          pf[qq][kk][0] = (short)f2bf(e0);
          pf[qq][kk][1] = (short)f2bf(e1);
          pf[qq][kk][2] = (short)f2bf(e2);
          pf[qq][kk][3] = (short)f2bf(e3);
        }
        ps += __shfl_xor(ps, 16);
        ps += __shfl_xor(ps, 32);
        lst[qq] = lst[qq] * alpha[qq] + ps;
      }
#pragma unroll
      for (int qq = 0; qq < 2; qq++) {
        if (!__all(alpha[qq] == 1.0f)) {
          float a = alpha[qq];
#pragma unroll
          for (int df = 0; df < 8; df++) of[qq][df] *= a;
        }
      }
#pragma unroll
      for (int df = 0; df < 8; df++) {
        s16x4 vf[4];
#pragma unroll
        for (int kk = 0; kk < 4; kk++)
          vf[kk] = *(const s16x4*)&Vt[(df * 16 + l15) * 64 +
                                      ((kk * 2 + (quad >> 1)) ^ (l15 & 7)) * 8 +
                                      (quad & 1) * 4];
#pragma unroll
        for (int qq = 0; qq < 2; qq++)
#pragma unroll
          for (int kk = 0; kk < 4; kk++)
            of[qq][df] = mfma16k16(vf[kk], pf[qq][kk], of[qq][df]);
      }
    }
  }
  const int b = bh >> 4, h = bh & 15;
#pragma unroll
  for (int qq = 0; qq < 2; qq++) {
    float linv = 1.0f / lst[qq];
    const size_t row = (size_t)(b * 2048 + q0 + w * 32 + qq * 16 + l15);
#pragma unroll
    for (int df = 0; df < 8; df++) {
      s16x4 o;
#pragma unroll
      for (int rg = 0; rg < 4; rg++) o[rg] = (short)f2bf(of[qq][df][rg] * linv);
      *(s16x4*)(attno + row * 2048 + h * 128 + df * 16 + quad * 4) = o;
    }
  }
}

extern "C" void kernel_launch(void* const* d_in, const int* in_sizes, int n_in,
                              void* d_out, int out_size, void* d_ws, size_t ws_size,
                              hipStream_t stream) {
  const float* x = (const float*)d_in[0];
  const float* Wqkv = (const float*)d_in[1];
  const float* Wout = (const float*)d_in[2];
  const float* cosT = (const float*)d_in[3];
  const float* sinT = (const float*)d_in[4];
  float* out = (float*)d_out;
  char* ws = (char*)d_ws;
  // workspace (96 MiB), lifetime-based reuse:
  //   [0,        50331648)  qkvh: q | k | vT (vT = per-head transposed v)
  //   [50331648, 58720256)  woutb (persists to gemm2)
  //   [58720256, 75497472)  xb (dead after gemm1)
  //   [75497472,100663296)  wqkvb (dead after gemm1) -> reused as attno
  u16* qkvh = (u16*)(ws + 0);
  u16* woutb = (u16*)(ws + 50331648);
  u16* xb = (u16*)(ws + 58720256);
  u16* wqkvb = (u16*)(ws + 75497472);
  u16* attno = wqkvb;

  cvt_all<<<12288, 256, 0, stream>>>(x, Wqkv, Wout, xb, wqkvb, woutb);
  gemm_qkv<<<384, 512, 0, stream>>>(xb, wqkvb, qkvh);
  rope_k<<<8192, 256, 0, stream>>>(qkvh, qkvh + 8388608, cosT, sinT);
  attn_k<<<512, 256, 0, stream>>>(qkvh, qkvh + 8388608, qkvh + 16777216, attno);
  gemm_bt<1><<<dim3(16, 32), 256, 0, stream>>>(attno, woutb, 2048, (void*)out, 2048);
}

// Round 4
// 407.422 us; speedup vs baseline: 1.0033x; 1.0033x over previous
//
#include <hip/hip_runtime.h>
#include <stdint.h>

typedef unsigned short u16;
typedef __attribute__((ext_vector_type(8))) short short8;
typedef __attribute__((ext_vector_type(4))) short s16x4;
typedef __attribute__((ext_vector_type(4))) float f32x4;
typedef __attribute__((ext_vector_type(16))) float f32x16;

__device__ __forceinline__ u16 f2bf(float f) {
  uint32_t x = __float_as_uint(f);
  x += 0x7fff + ((x >> 16) & 1);
  return (u16)(x >> 16);
}
__device__ __forceinline__ float bf2f(u16 u) {
  return __uint_as_float(((uint32_t)u) << 16);
}
__device__ __forceinline__ f32x4 mfma16(short8 a, short8 b, f32x4 c) {
  return __builtin_amdgcn_mfma_f32_16x16x32_bf16(a, b, c, 0, 0, 0);
}
__device__ __forceinline__ f32x16 mfma32(short8 a, short8 b, f32x16 c) {
  return __builtin_amdgcn_mfma_f32_32x32x16_bf16(a, b, c, 0, 0, 0);
}
__device__ __forceinline__ f32x4 mfma16k16(s16x4 a, s16x4 b, f32x4 c) {
  return __builtin_amdgcn_mfma_f32_16x16x16bf16_1k(a, b, c, 0, 0, 0);
}
__device__ __forceinline__ void gld16(const u16* g, u16* l) {
  __builtin_amdgcn_global_load_lds(
      (const __attribute__((address_space(1))) unsigned int*)g,
      (__attribute__((address_space(3))) unsigned int*)l, 16, 0, 0);
}
__device__ __forceinline__ float exp2a(float x) {  // raw v_exp_f32 (2^x)
  float r;
  asm("v_exp_f32 %0, %1" : "=v"(r) : "v"(x));
  return r;
}

#define WAIT_VM(n) asm volatile("s_waitcnt vmcnt(" #n ")" ::: "memory")

// ---------------- fused fp32 -> bf16 conversion (x | Wqkv | Wout) ----------------
__global__ __launch_bounds__(256) void cvt_all(const float* __restrict__ x,
                                               const float* __restrict__ wqkv,
                                               const float* __restrict__ wout,
                                               u16* __restrict__ xb,
                                               u16* __restrict__ wqkvb,
                                               u16* __restrict__ woutb) {
  long i = ((long)blockIdx.x * 256 + threadIdx.x) * 8;
  const float* s;
  u16* d;
  long off;
  if (i < 8388608) {
    s = x; d = xb; off = i;
  } else if (i < 20971520) {
    s = wqkv; d = wqkvb; off = i - 8388608;
  } else {
    s = wout; d = woutb; off = i - 20971520;
  }
  f32x4 a = *(const f32x4*)(s + off);
  f32x4 b = *(const f32x4*)(s + off + 4);
  short8 o;
#pragma unroll
  for (int j = 0; j < 4; j++) {
    o[j] = (short)f2bf(a[j]);
    o[j + 4] = (short)f2bf(b[j]);
  }
  *(short8*)(d + off) = o;
}

// ---------------- QKV GEMM: 256x256 tile, 8 waves, BK=32, 4-ring LDS ----------------
// C = A(4096x2048) * B(6144x2048)^T, bf16 BT layout. K = 2048 -> 64 K-tiles.
// Round-4 change: 4-phase SNAKE REGISTER PIPELINE. Rounds 2/3 measured full
// LDS-pipe/MFMA-pipe serialization (~3000 cyc/tile = reads 1540 + MFMA 1242, serial)
// regardless of barrier structure: every wave's ds_reads preceded all its MFMAs for
// the same data, so the compiler's lgkm wait serialized the pipes per wave (and all
// waves are tile-aligned). Fix (the real m201 mechanism): each phase's MFMA cluster
// consumes fragments loaded 1-2 phases EARLIER, and issues the reads for later
// phases -- LDS services reads while the MFMA pipe crunches.
//   ph0: A_lo x B_lo (reads A_hi of tile tau)
//   ph1: A_hi x B_lo (reads B_hi of tau)
//   ph2: A_hi x B_hi (reads A_lo of tau+1, ring (tau+1)&3)
//   ph3: A_lo x B_hi (reads B_lo of tau+1)
// One barrier per tile. Cross-wave safety for reading ring tau+1 during tile tau:
// end-of-tile wait is vmcnt(4) -> stage(tau+1) (issued 2 tiles ago) landed in EVERY
// wave before the barrier; stage(tau+3) (issued this tile) stays in flight (T4,
// never drains in steady state). Ring r's last read is during tile r (ph0/ph1,
// lgkm-consumed before barrier r); next write to r issues during tile r+1 -> safe.
// Tail: vmcnt(4) at tau=60, vmcnt(0) at 61.
// LDS chunk swizzle (validated round-2, 0 bank conflicts): stored 16B chunk at row
// r, position p holds global chunk (p - (r>>1)) & 3; staging permutes the per-lane
// GLOBAL source chunk; fragment reads use position ((quad + (l15>>1)) & 3).
// Epilogue: q (scaled by 1/sqrt(128)*log2e) & k head-major [B,H,T,128] scatter;
//           v transposed per head [B,H,128,T] (8B stores along t).
__global__ __launch_bounds__(512, 2) void gemm_qkv(const u16* __restrict__ A,
                                                   const u16* __restrict__ Bw,
                                                   u16* __restrict__ q3) {
  __shared__ __align__(16) u16 SA[32768];  // 4 rings x [256 rows][32 k] bf16 = 64 KiB
  __shared__ __align__(16) u16 SB[32768];  // 64 KiB
  // bijective XCD swizzle (nwg=384, 8 XCDs x 48): each XCD owns 3 n-panels x 16 m
  const int id = blockIdx.x;
  const int swz = (id & 7) * 48 + (id >> 3);
  const int by = swz & 15, bx = swz >> 4;
  const int m0 = by * 256, n0 = bx * 256;
  const int t = threadIdx.x, w = t >> 6, lane = t & 63;
  const int quad = lane >> 4, l15 = lane & 15;
  const int wm = w >> 2, wn = w & 3;  // 2 x 4 wave grid; per-wave C = 128 x 64
  // staging: thread t -> row rS = t>>2 (and rS+128), LDS position pS = t&3.
  const int rS = t >> 2, pS = t & 3;
  const int cS = (pS - (rS >> 1)) & 3;
  const size_t arow = (size_t)(m0 + rS) * 2048 + cS * 8;
  const size_t brow = (size_t)(n0 + rS) * 2048 + cS * 8;

  f32x4 acc[8][4] = {};
  // fragment-read swizzled chunk position (row bases multiples of 16 -> lane-uniform)
  const int pq = ((quad + (l15 >> 1)) & 3) * 8;

#define STAGE_PAIR(KT)                                                        \
  {                                                                           \
    const u16* ga_ = A + arow + (size_t)(KT) * 32;                            \
    u16* la_ = SA + ((KT) & 3) * 8192 + t * 8;                                \
    gld16(ga_, la_);                                                          \
    gld16(ga_ + (size_t)128 * 2048, la_ + 4096);                              \
    const u16* gb_ = Bw + brow + (size_t)(KT) * 32;                           \
    u16* lb_ = SB + ((KT) & 3) * 8192 + t * 8;                                \
    gld16(gb_, lb_);                                                          \
    gld16(gb_ + (size_t)128 * 2048, lb_ + 4096);                              \
  }

  // persistent cross-tile fragment sets (A_lo[4] + B_lo[2], double-buffered)
  short8 aflo0[4], bflo0[2], aflo1[4], bflo1[2];

// One K-tile: 4-phase snake. MFMA cluster of each phase uses regs loaded >=1 phase
// earlier; reads for tau+1's ph0 issue from ring RN during ph2/ph3.
#define TILE(RC, RN, TAU, ALO_C, BLO_C, ALO_N, BLO_N, DO_STAGE, DO_PREF, WAIT)   \
  {                                                                              \
    const u16* Sa_ = SA + (RC) * 8192;                                           \
    const u16* Sb_ = SB + (RC) * 8192;                                           \
    const u16* San_ = SA + (RN) * 8192;                                          \
    const u16* Sbn_ = SB + (RN) * 8192;                                          \
    if (DO_STAGE) STAGE_PAIR((TAU) + 3);                                         \
    short8 afhi[4], bfhi[2];                                                     \
    _Pragma("unroll") for (int i = 0; i < 4; i++)                                \
        afhi[i] = *(const short8*)&Sa_[(wm * 128 + 64 + i * 16 + l15) * 32 + pq];\
    __builtin_amdgcn_s_setprio(1);                                               \
    _Pragma("unroll") for (int mi = 0; mi < 4; mi++)                             \
      _Pragma("unroll") for (int ni = 0; ni < 2; ni++)                           \
          acc[mi][ni] = mfma16(ALO_C[mi], BLO_C[ni], acc[mi][ni]);               \
    __builtin_amdgcn_s_setprio(0);                                               \
    _Pragma("unroll") for (int n = 0; n < 2; n++)                                \
        bfhi[n] = *(const short8*)&Sb_[(wn * 64 + (n + 2) * 16 + l15) * 32 + pq];\
    __builtin_amdgcn_s_setprio(1);                                               \
    _Pragma("unroll") for (int mi = 0; mi < 4; mi++)                             \
      _Pragma("unroll") for (int ni = 0; ni < 2; ni++)                           \
          acc[4 + mi][ni] = mfma16(afhi[mi], BLO_C[ni], acc[4 + mi][ni]);        \
    __builtin_amdgcn_s_setprio(0);                                               \
    if (DO_PREF) {                                                               \
      _Pragma("unroll") for (int i = 0; i < 4; i++)                              \
          ALO_N[i] = *(const short8*)&San_[(wm * 128 + i * 16 + l15) * 32 + pq]; \
    }                                                                            \
    __builtin_amdgcn_s_setprio(1);                                               \
    _Pragma("unroll") for (int mi = 0; mi < 4; mi++)                             \
      _Pragma("unroll") for (int ni = 0; ni < 2; ni++)                           \
          acc[4 + mi][2 + ni] = mfma16(afhi[mi], bfhi[ni], acc[4 + mi][2 + ni]); \
    __builtin_amdgcn_s_setprio(0);                                               \
    if (DO_PREF) {                                                               \
      _Pragma("unroll") for (int n = 0; n < 2; n++)                              \
          BLO_N[n] = *(const short8*)&Sbn_[(wn * 64 + n * 16 + l15) * 32 + pq];  \
    }                                                                            \
    __builtin_amdgcn_s_setprio(1);                                               \
    _Pragma("unroll") for (int mi = 0; mi < 4; mi++)                             \
      _Pragma("unroll") for (int ni = 0; ni < 2; ni++)                           \
          acc[mi][2 + ni] = mfma16(ALO_C[mi], bfhi[ni], acc[mi][2 + ni]);        \
    __builtin_amdgcn_s_setprio(0);                                               \
    WAIT;                                                                        \
    __builtin_amdgcn_s_barrier();                                                \
  }

  // prologue: stage tiles 0,1,2 (12 loads); vmcnt(4) -> tiles 0,1 landed; then
  // pre-load tile-0's A_lo/B_lo fragments from ring 0.
  STAGE_PAIR(0);
  STAGE_PAIR(1);
  STAGE_PAIR(2);
  WAIT_VM(4);
  __builtin_amdgcn_s_barrier();
#pragma unroll
  for (int i = 0; i < 4; i++)
    aflo0[i] = *(const short8*)&SA[(wm * 128 + i * 16 + l15) * 32 + pq];
#pragma unroll
  for (int n = 0; n < 2; n++)
    bflo0[n] = *(const short8*)&SB[(wn * 64 + n * 16 + l15) * 32 + pq];

#pragma unroll 1
  for (int kt = 0; kt < 60; kt += 4) {
    TILE(0, 1, kt + 0, aflo0, bflo0, aflo1, bflo1, 1, 1, WAIT_VM(4));
    TILE(1, 2, kt + 1, aflo1, bflo1, aflo0, bflo0, 1, 1, WAIT_VM(4));
    TILE(2, 3, kt + 2, aflo0, bflo0, aflo1, bflo1, 1, 1, WAIT_VM(4));
    TILE(3, 0, kt + 3, aflo1, bflo1, aflo0, bflo0, 1, 1, WAIT_VM(4));
  }
  // tail: tau=60 stages tile 63; drain vmcnt 4 -> 0; last tiles don't stage/prefetch
  TILE(0, 1, 60, aflo0, bflo0, aflo1, bflo1, 1, 1, WAIT_VM(4));
  TILE(1, 2, 61, aflo1, bflo1, aflo0, bflo0, 0, 1, WAIT_VM(0));
  TILE(2, 3, 62, aflo0, bflo0, aflo1, bflo1, 0, 1, (void)0);
  TILE(3, 0, 63, aflo1, bflo1, aflo0, bflo0, 0, 0, (void)0);
#undef TILE
#undef STAGE_PAIR

  // ---- epilogue: scatter into q | k | vT (layouts match rope_k / attn_k) ----
  // C row = m0 + wm*128 + (mi&4)*16 + (mi&3)*16 + quad*4 + r  (mi 0-3 lo, 4-7 hi)
  // C col = n0 + wn*64 + ni*16 + l15
  const int which = n0 >> 11;  // 0=q 1=k 2=v (2048 % 256 == 0 -> block-uniform)
  const int bb = m0 >> 11, tt0 = m0 & 2047;
  if (which == 2) {
    u16* vbase = q3 + 16777216;
#pragma unroll
    for (int ni = 0; ni < 4; ni++) {
      const int gcol = (n0 & 2047) + wn * 64 + ni * 16 + l15;
      const int hh = gcol >> 7, di = gcol & 127;
      u16* vb = vbase + ((size_t)(bb * 16 + hh) * 128 + di) * 2048;
#pragma unroll
      for (int mi = 0; mi < 8; mi++) {
        const int mrow = (mi < 4) ? mi * 16 : 64 + (mi - 4) * 16;
        const int tloc = tt0 + wm * 128 + mrow + quad * 4;
        s16x4 st;
#pragma unroll
        for (int r = 0; r < 4; r++) st[r] = (short)f2bf(acc[mi][ni][r]);
        *(s16x4*)(vb + tloc) = st;  // 4 consecutive t -> 8B store
      }
    }
  } else {
    const float sc = (which == 0) ? 0.1275174f : 1.0f;  // 1/sqrt(128)*log2(e)
    u16* base = q3 + (size_t)which * 8388608;
#pragma unroll
    for (int ni = 0; ni < 4; ni++) {
      const int gcol = (n0 & 2047) + wn * 64 + ni * 16 + l15;
      const int hh = gcol >> 7, di = gcol & 127;
      u16* qb = base + ((size_t)(bb * 16 + hh) * 2048) * 128 + di;
#pragma unroll
      for (int mi = 0; mi < 8; mi++) {
        const int mrow = (mi < 4) ? mi * 16 : 64 + (mi - 4) * 16;
        const int tloc = tt0 + wm * 128 + mrow + quad * 4;
#pragma unroll
        for (int r = 0; r < 4; r++)
          qb[(size_t)(tloc + r) * 128] = f2bf(acc[mi][ni][r] * sc);
      }
    }
  }
}

// ---------------- BT GEMM (kept for the output projection), 32x32x16 MFMA --------
template <int EPI>
__global__ __launch_bounds__(256) void gemm_bt(const u16* __restrict__ A,
                                               const u16* __restrict__ B,
                                               int K, void* __restrict__ Cv, int N) {
  __shared__ __align__(16) u16 SMEM[8448];  // staging 16KB; EPI=1 epilogue f32[32][132]
  u16* As = SMEM;
  u16* Bs = SMEM + 4096;
  const int m0 = blockIdx.y * 128, n0 = blockIdx.x * 128;
  const int t = threadIdx.x, w = t >> 6, lane = t & 63;
  const int l31 = lane & 31, half = lane >> 5;
  const int rb = (w >> 1) * 64, cb = (w & 1) * 64;
  f32x16 acc[2][2] = {};
  const int rowS = w * 16 + (lane >> 2);                // staged row (0..63, +64 second)
  const int cS = ((lane & 3) - (rowS >> 1)) & 3;        // swizzled source chunk
  const u16* ag = A + (size_t)(m0 + rowS) * K + cS * 8;
  const u16* bg = B + (size_t)(n0 + rowS) * K + cS * 8;
  u16* al = As + w * 512 + lane * 8;  // lane-contiguous: base + lane*16B
  u16* bl = Bs + w * 512 + lane * 8;
  const size_t rowskip = (size_t)64 * K;
  const int p0 = ((0 * 2 + half + (l31 >> 1)) & 3) * 8;  // kh=0
  const int p1 = ((1 * 2 + half + (l31 >> 1)) & 3) * 8;  // kh=1
  for (int k0 = 0; k0 < K; k0 += 32) {
    __syncthreads();
    gld16(ag, al);
    gld16(ag + rowskip, al + 2048);
    gld16(bg, bl);
    gld16(bg + rowskip, bl + 2048);
    ag += 32;
    bg += 32;
    __syncthreads();
    short8 af[2][2], bfr[2][2];
#pragma unroll
    for (int mi = 0; mi < 2; mi++) {
      af[mi][0] = *(const short8*)&As[(rb + mi * 32 + l31) * 32 + p0];
      af[mi][1] = *(const short8*)&As[(rb + mi * 32 + l31) * 32 + p1];
    }
#pragma unroll
    for (int ni = 0; ni < 2; ni++) {
      bfr[ni][0] = *(const short8*)&Bs[(cb + ni * 32 + l31) * 32 + p0];
      bfr[ni][1] = *(const short8*)&Bs[(cb + ni * 32 + l31) * 32 + p1];
    }
#pragma unroll
    for (int kh = 0; kh < 2; kh++)
#pragma unroll
      for (int mi = 0; mi < 2; mi++)
#pragma unroll
        for (int ni = 0; ni < 2; ni++)
          acc[mi][ni] = mfma32(af[mi][kh], bfr[ni][kh], acc[mi][ni]);
  }

  if (EPI == 0) {
    const int which = n0 >> 11;
    const int hh = (n0 & 2047) >> 7;
    const int bb = m0 >> 11, tt0 = m0 & 2047;
    u16* q3 = (u16*)Cv;
    if (which == 2) {
      u16* vbase = q3 + 16777216 + ((size_t)(bb * 16 + hh) * 128) * 2048;
#pragma unroll
      for (int mi = 0; mi < 2; mi++)
#pragma unroll
        for (int ni = 0; ni < 2; ni++) {
          int di = cb + ni * 32 + l31;
          int trow = tt0 + rb + mi * 32 + half * 4;
#pragma unroll
          for (int rg2 = 0; rg2 < 4; rg2++) {
            s16x4 st;
#pragma unroll
            for (int j = 0; j < 4; j++) st[j] = (short)f2bf(acc[mi][ni][rg2 * 4 + j]);
            *(s16x4*)(vbase + (size_t)di * 2048 + trow + rg2 * 8) = st;
          }
        }
    } else {
      const float sc = (which == 0) ? 0.1275174f : 1.0f;
      u16* base = q3 + (size_t)which * 8388608 + ((size_t)(bb * 16 + hh) * 2048) * 128;
#pragma unroll
      for (int mi = 0; mi < 2; mi++)
#pragma unroll
        for (int ni = 0; ni < 2; ni++) {
          int di = cb + ni * 32 + l31;
          int trow = tt0 + rb + mi * 32 + half * 4;
#pragma unroll
          for (int reg = 0; reg < 16; reg++) {
            int tt = trow + (reg & 3) + 8 * (reg >> 2);
            base[(size_t)tt * 128 + di] = f2bf(acc[mi][ni][reg] * sc);
          }
        }
    }
  } else {
    float* Es = (float*)SMEM;  // [32][132]
    float* C = (float*)Cv;
#pragma unroll
    for (int r = 0; r < 4; r++) {
      __syncthreads();
      if ((w >> 1) == (r >> 1)) {
        const int mi = r & 1;
#pragma unroll
        for (int ni = 0; ni < 2; ni++) {
          int col = cb + ni * 32 + l31;
#pragma unroll
          for (int reg = 0; reg < 16; reg++) {
            int lrow = (reg & 3) + 8 * (reg >> 2) + half * 4;
            Es[lrow * 132 + col] = acc[mi][ni][reg];
          }
        }
      }
      __syncthreads();
#pragma unroll
      for (int it = 0; it < 4; it++) {
        int idx = it * 256 + t;
        int row = idx >> 5, ch = idx & 31;
        f32x4 vv = *(const f32x4*)&Es[row * 132 + ch * 4];
        *(f32x4*)&C[(size_t)(m0 + r * 32 + row) * N + n0 + ch * 4] = vv;
      }
    }
  }
}

// ---------------- RoPE in-place on q,k (heads 0..7 only) ----------------
__global__ __launch_bounds__(256) void rope_k(u16* __restrict__ q, u16* __restrict__ k,
                                              const float* __restrict__ cosT,
                                              const float* __restrict__ sinT) {
  int t = threadIdx.x;
  int row = blockIdx.x * 4 + (t >> 6);  // over (b, h<8, tpos)
  int i = t & 63;
  int b = row >> 14;
  int h = (row >> 11) & 7;
  int tp = row & 2047;
  size_t base = ((size_t)((b * 16 + h) * 2048 + tp)) * 128 + 2 * i;
  float c = cosT[tp * 64 + i], s = sinT[tp * 64 + i];
  {
    uint32_t u = *(uint32_t*)(q + base);
    float x0 = bf2f((u16)(u & 0xffff)), x1 = bf2f((u16)(u >> 16));
    float re = x0 * c - x1 * s, im = x0 * s + x1 * c;
    *(uint32_t*)(q + base) = (uint32_t)f2bf(re) | ((uint32_t)f2bf(im) << 16);
  }
  {
    uint32_t u = *(uint32_t*)(k + base);
    float x0 = bf2f((u16)(u & 0xffff)), x1 = bf2f((u16)(u >> 16));
    float re = x0 * c - x1 * s, im = x0 * s + x1 * c;
    *(uint32_t*)(k + base) = (uint32_t)f2bf(re) | ((uint32_t)f2bf(im) << 16);
  }
}

// ---------------- flash attention, S^T orientation ----------------
__global__ __launch_bounds__(256, 2) void attn_k(const u16* __restrict__ qh,
                                                 const u16* __restrict__ kh,
                                                 const u16* __restrict__ vTh,
                                                 u16* __restrict__ attno) {
  __shared__ __align__(16) u16 Ks[8192];  // 64 keys x 128 d, XOR-swizzled 16B chunks
  __shared__ __align__(16) u16 Vt[8192];  // 128 d x 64 keys, XOR-swizzled 16B chunks
  const int i = blockIdx.x;
  const int jj = i & 255, half = i >> 8;
  const int bh = jj >> 3, t8 = jj & 7;
  const int qt = half ? (15 - t8) : t8;
  const int q0 = qt * 128;
  const int t = threadIdx.x, w = t >> 6, lane = t & 63;
  const int quad = lane >> 4, l15 = lane & 15;
  const size_t bhoff = (size_t)bh * 262144;

  short8 qb[2][4];
  {
    const u16* qp = qh + bhoff + (size_t)(q0 + w * 32 + l15) * 128 + quad * 8;
#pragma unroll
    for (int qq = 0; qq < 2; qq++)
#pragma unroll
      for (int ks = 0; ks < 4; ks++)
        qb[qq][ks] = *(const short8*)(qp + qq * 2048 + ks * 32);
  }
  f32x4 of[2][8] = {};
  float mst[2] = {-1e30f, -1e30f}, lst[2] = {0.f, 0.f};
  const int nkt = 2 * qt + 2;
  const int wq0 = q0 + w * 32;

  for (int kt = 0; kt < nkt; kt++) {
    const int k0 = kt * 64;
    __syncthreads();
    {
#pragma unroll
      for (int it = 0; it < 4; it++) {  // K: 64 rows x 16 chunks
        int L = it * 256 + t;
        int key = L >> 4, c = L & 15;
        gld16(kh + bhoff + (size_t)(k0 + key) * 128 + ((c ^ (key & 15)) * 8),
              Ks + (size_t)L * 8);
      }
#pragma unroll
      for (int it = 0; it < 4; it++) {  // V^T: 128 rows x 8 chunks
        int L = it * 256 + t;
        int d = L >> 3, c = L & 7;
        gld16(vTh + bhoff + (size_t)d * 2048 + k0 + ((c ^ (d & 7)) * 8),
              Vt + (size_t)L * 8);
      }
    }
    __syncthreads();
    if (k0 <= wq0 + 31) {
      f32x4 sacc[2][4];
#pragma unroll
      for (int qq = 0; qq < 2; qq++)
#pragma unroll
        for (int kk = 0; kk < 4; kk++) sacc[qq][kk] = (f32x4){0.f, 0.f, 0.f, 0.f};
#pragma unroll
      for (int kk = 0; kk < 4; kk++) {
        short8 kf[4];
#pragma unroll
        for (int ks = 0; ks < 4; ks++)
          kf[ks] = *(const short8*)&Ks[(kk * 16 + l15) * 128 + ((ks * 4 + quad) ^ l15) * 8];
#pragma unroll
        for (int qq = 0; qq < 2; qq++)
#pragma unroll
          for (int ks = 0; ks < 4; ks++)
            sacc[qq][kk] = mfma16(kf[ks], qb[qq][ks], sacc[qq][kk]);
      }
      const bool needmask = (k0 + 63 > wq0);
      s16x4 pf[2][4];
      float alpha[2];
#pragma unroll
      for (int qq = 0; qq < 2; qq++) {
        const int qg = wq0 + qq * 16 + l15;
        if (needmask) {
#pragma unroll
          for (int kk = 0; kk < 4; kk++)
#pragma unroll
            for (int rg = 0; rg < 4; rg++)
              if (k0 + kk * 16 + quad * 4 + rg > qg) sacc[qq][kk][rg] = -1e30f;
        }
        float pm = -1e30f;
#pragma unroll
        for (int kk = 0; kk < 4; kk++)
#pragma unroll
          for (int rg = 0; rg < 4; rg++) pm = fmaxf(pm, sacc[qq][kk][rg]);
        pm = fmaxf(pm, __shfl_xor(pm, 16));
        pm = fmaxf(pm, __shfl_xor(pm, 32));
        float mnew = fmaxf(mst[qq], pm);
        alpha[qq] = exp2a(mst[qq] - mnew);
        mst[qq] = mnew;
        float ps = 0.f;
#pragma unroll
        for (int kk = 0; kk < 4; kk++) {
          float e0 = exp2a(sacc[qq][kk][0] - mnew);
          float e1 = exp2a(sacc[qq][kk][1] - mnew);
          float e2 = exp2a(sacc[qq][kk][2] - mnew);
          float e3 = exp2a(sacc[qq][kk][3] - mnew);
          ps += (e0 + e1) + (e2 + e3);
          pf[qq][kk][0] = (short)f2bf(e0);
          pf[qq][kk][1] = (short)f2bf(e1);
          pf[qq][kk][2] = (short)f2bf(e2);
          pf[qq][kk][3] = (short)f2bf(e3);
        }
        ps += __shfl_xor(ps, 16);
        ps += __shfl_xor(ps, 32);
        lst[qq] = lst[qq] * alpha[qq] + ps;
      }
#pragma unroll
      for (int qq = 0; qq < 2; qq++) {
        if (!__all(alpha[qq] == 1.0f)) {
          float a = alpha[qq];
#pragma unroll
          for (int df = 0; df < 8; df++) of[qq][df] *= a;
        }
      }
#pragma unroll
      for (int df = 0; df < 8; df++) {
        s16x4 vf[4];
#pragma unroll
        for (int kk = 0; kk < 4; kk++)
          vf[kk] = *(const s16x4*)&Vt[(df * 16 + l15) * 64 +
                                      ((kk * 2 + (quad >> 1)) ^ (l15 & 7)) * 8 +
                                      (quad & 1) * 4];
#pragma unroll
        for (int qq = 0; qq < 2; qq++)
#pragma unroll
          for (int kk = 0; kk < 4; kk++)
            of[qq][df] = mfma16k16(vf[kk], pf[qq][kk], of[qq][df]);
      }
    }
  }
  const int b = bh >> 4, h = bh & 15;
#pragma unroll
  for (int qq = 0; qq < 2; qq++) {
    float linv = 1.0f / lst[qq];
    const size_t row = (size_t)(b * 2048 + q0 + w * 32 + qq * 16 + l15);
#pragma unroll
    for (int df = 0; df < 8; df++) {
      s16x4 o;
#pragma unroll
      for (int rg = 0; rg < 4; rg++) o[rg] = (short)f2bf(of[qq][df][rg] * linv);
      *(s16x4*)(attno + row * 2048 + h * 128 + df * 16 + quad * 4) = o;
    }
  }
}

extern "C" void kernel_launch(void* const* d_in, const int* in_sizes, int n_in,
                              void* d_out, int out_size, void* d_ws, size_t ws_size,
                              hipStream_t stream) {
  const float* x = (const float*)d_in[0];
  const float* Wqkv = (const float*)d_in[1];
  const float* Wout = (const float*)d_in[2];
  const float* cosT = (const float*)d_in[3];
  const float* sinT = (const float*)d_in[4];
  float* out = (float*)d_out;
  char* ws = (char*)d_ws;
  // workspace (96 MiB), lifetime-based reuse:
  //   [0,        50331648)  qkvh: q | k | vT (vT = per-head transposed v)
  //   [50331648, 58720256)  woutb (persists to gemm2)
  //   [58720256, 75497472)  xb (dead after gemm1)
  //   [75497472,100663296)  wqkvb (dead after gemm1) -> reused as attno
  u16* qkvh = (u16*)(ws + 0);
  u16* woutb = (u16*)(ws + 50331648);
  u16* xb = (u16*)(ws + 58720256);
  u16* wqkvb = (u16*)(ws + 75497472);
  u16* attno = wqkvb;

  cvt_all<<<12288, 256, 0, stream>>>(x, Wqkv, Wout, xb, wqkvb, woutb);
  gemm_qkv<<<384, 512, 0, stream>>>(xb, wqkvb, qkvh);
  rope_k<<<8192, 256, 0, stream>>>(qkvh, qkvh + 8388608, cosT, sinT);
  attn_k<<<512, 256, 0, stream>>>(qkvh, qkvh + 8388608, qkvh + 16777216, attno);
  gemm_bt<1><<<dim3(16, 32), 256, 0, stream>>>(attno, woutb, 2048, (void*)out, 2048);
}

// Round 5
// 395.228 us; speedup vs baseline: 1.0342x; 1.0309x over previous
//
#include <hip/hip_runtime.h>
#include <stdint.h>

typedef unsigned short u16;
typedef __attribute__((ext_vector_type(8))) short short8;
typedef __attribute__((ext_vector_type(4))) short s16x4;
typedef __attribute__((ext_vector_type(4))) float f32x4;
typedef __attribute__((ext_vector_type(16))) float f32x16;

__device__ __forceinline__ u16 f2bf(float f) {
  uint32_t x = __float_as_uint(f);
  x += 0x7fff + ((x >> 16) & 1);
  return (u16)(x >> 16);
}
__device__ __forceinline__ float bf2f(u16 u) {
  return __uint_as_float(((uint32_t)u) << 16);
}
__device__ __forceinline__ f32x4 mfma16(short8 a, short8 b, f32x4 c) {
  return __builtin_amdgcn_mfma_f32_16x16x32_bf16(a, b, c, 0, 0, 0);
}
__device__ __forceinline__ f32x16 mfma32(short8 a, short8 b, f32x16 c) {
  return __builtin_amdgcn_mfma_f32_32x32x16_bf16(a, b, c, 0, 0, 0);
}
__device__ __forceinline__ f32x4 mfma16k16(s16x4 a, s16x4 b, f32x4 c) {
  return __builtin_amdgcn_mfma_f32_16x16x16bf16_1k(a, b, c, 0, 0, 0);
}
__device__ __forceinline__ void gld16(const u16* g, u16* l) {
  __builtin_amdgcn_global_load_lds(
      (const __attribute__((address_space(1))) unsigned int*)g,
      (__attribute__((address_space(3))) unsigned int*)l, 16, 0, 0);
}
__device__ __forceinline__ float exp2a(float x) {  // raw v_exp_f32 (2^x)
  float r;
  asm("v_exp_f32 %0, %1" : "=v"(r) : "v"(x));
  return r;
}

#define WAIT_VM(n) asm volatile("s_waitcnt vmcnt(" #n ")" ::: "memory")

// ---------------- fused fp32 -> bf16 conversion (x | Wqkv | Wout) ----------------
__global__ __launch_bounds__(256) void cvt_all(const float* __restrict__ x,
                                               const float* __restrict__ wqkv,
                                               const float* __restrict__ wout,
                                               u16* __restrict__ xb,
                                               u16* __restrict__ wqkvb,
                                               u16* __restrict__ woutb) {
  long i = ((long)blockIdx.x * 256 + threadIdx.x) * 8;
  const float* s;
  u16* d;
  long off;
  if (i < 8388608) {
    s = x; d = xb; off = i;
  } else if (i < 20971520) {
    s = wqkv; d = wqkvb; off = i - 8388608;
  } else {
    s = wout; d = woutb; off = i - 20971520;
  }
  f32x4 a = *(const f32x4*)(s + off);
  f32x4 b = *(const f32x4*)(s + off + 4);
  short8 o;
#pragma unroll
  for (int j = 0; j < 4; j++) {
    o[j] = (short)f2bf(a[j]);
    o[j + 4] = (short)f2bf(b[j]);
  }
  *(short8*)(d + off) = o;
}

// ---------------- QKV GEMM: 128x256 tile, 8 waves, BK=32, 3-ring LDS ----------------
// C = A(4096x2048) * B(6144x2048)^T, bf16 BT layout. K = 2048 -> 64 K-tiles.
// Round-5 change: RESOURCE BALANCE, not schedule. Rounds 2-4 proved three different
// source schedules (2-phase barriered / free-run / snake reg pipeline) all land at
// ~2900 cyc/tile = LDS(1500) + MFMA(1242) fully SERIAL: with 1 block/CU (128 KiB
// LDS) there is no second instruction stream to fill either pipe during the other's
// turn. Fix: 72 KiB LDS (3-ring x (A 8KB + B 16KB)) -> 2 blocks/CU; co-resident
// blocks anti-phase, so one block's MFMA burst covers the other's LDS/stage stall
// (m114 implicit overlap -- the mechanism the 128-KiB design structurally removed).
// Wave-tile 64x64 (acc = 64 VGPR) so 8 waves fit 128 regs/wave:
// __launch_bounds__(512,4) -> 16 waves/CU. Grid 32x24 = 768 blocks = exactly
// 3 x 256 CUs -> 100% packing (384-block 256^2 grid was pinned at 75%).
// Counted vmcnt: 3 loads/tile/thread; steady wait vmcnt(3) keeps stage(tau+2) in
// flight; drains 3->0 only at the tail. Ring safety: stage(tau+2) targets ring
// (tau+2)%3 = (tau-1)%3, whose reads were consumed before barrier(tau-1).
// LDS chunk swizzle (validated: 0 bank conflicts): stored 16B chunk at row r,
// position p holds global chunk (p - (r>>1)) & 3; staging permutes the per-lane
// GLOBAL source chunk (LDS dest lane-contiguous as global_load_lds requires);
// fragment reads use position ((quad + (l15>>1)) & 3).
// Epilogue: q (scaled by 1/sqrt(128)*log2e) & k head-major [B,H,T,128] scatter;
//           v transposed per head [B,H,128,T] (8B stores along t).
__global__ __launch_bounds__(512, 4) void gemm_qkv(const u16* __restrict__ A,
                                                   const u16* __restrict__ Bw,
                                                   u16* __restrict__ q3) {
  __shared__ __align__(16) u16 SA[12288];  // 3 rings x [128 rows][32 k] = 24 KiB
  __shared__ __align__(16) u16 SB[24576];  // 3 rings x [256 rows][32 k] = 48 KiB
  // bijective XCD swizzle: 768 = 8 XCDs x 96; each XCD owns 3 n-panels x 32 m
  const int id = blockIdx.x;
  const int swz = (id & 7) * 96 + (id >> 3);
  const int by = swz & 31, bx = swz >> 5;
  const int m0 = by * 128, n0 = bx * 256;
  const int t = threadIdx.x, w = t >> 6, lane = t & 63;
  const int quad = lane >> 4, l15 = lane & 15;
  const int wm = w >> 2, wn = w & 3;  // 2 x 4 wave grid; per-wave C = 64 x 64
  // staging: thread t -> row rS = t>>2, LDS position pS = t&3;
  // source chunk cS = (pS - (rS>>1)) & 3; row rS+128 (B 2nd half): same cS (mod 4).
  const int rS = t >> 2, pS = t & 3;
  const int cS = (pS - (rS >> 1)) & 3;
  const size_t arowA = (size_t)(m0 + rS) * 2048 + cS * 8;
  const size_t arowB = (size_t)(n0 + rS) * 2048 + cS * 8;

  f32x4 acc[4][4] = {};  // 64 VGPR
  // fragment-read swizzled chunk position (row bases multiples of 16 -> lane-uniform)
  const int pq = ((quad + (l15 >> 1)) & 3) * 8;

#define STAGE(KT, RS_)                                   \
  {                                                      \
    const u16* ga_ = A + arowA + (size_t)(KT) * 32;      \
    gld16(ga_, SA + (RS_)*4096 + t * 8);                 \
    const u16* gb_ = Bw + arowB + (size_t)(KT) * 32;     \
    u16* lb_ = SB + (RS_)*8192 + t * 8;                  \
    gld16(gb_, lb_);                                     \
    gld16(gb_ + (size_t)128 * 2048, lb_ + 4096);         \
  }

// One K-tile: stage tau+2 -> 8 ds_read -> 16 MFMA -> counted wait -> barrier.
#define TILE(RC, RSS, TAU, DO_STAGE, WAIT)                                    \
  {                                                                           \
    const u16* Sa_ = SA + (RC)*4096;                                          \
    const u16* Sb_ = SB + (RC)*8192;                                          \
    if (DO_STAGE) STAGE((TAU) + 2, RSS);                                      \
    short8 af[4], bf[4];                                                      \
    _Pragma("unroll") for (int i = 0; i < 4; i++)                             \
        af[i] = *(const short8*)&Sa_[(wm * 64 + i * 16 + l15) * 32 + pq];     \
    _Pragma("unroll") for (int n = 0; n < 4; n++)                             \
        bf[n] = *(const short8*)&Sb_[(wn * 64 + n * 16 + l15) * 32 + pq];     \
    __builtin_amdgcn_s_setprio(1);                                            \
    _Pragma("unroll") for (int mi = 0; mi < 4; mi++)                          \
      _Pragma("unroll") for (int ni = 0; ni < 4; ni++)                        \
          acc[mi][ni] = mfma16(af[mi], bf[ni], acc[mi][ni]);                  \
    __builtin_amdgcn_s_setprio(0);                                            \
    WAIT;                                                                     \
    __builtin_amdgcn_s_barrier();                                             \
  }

  // prologue: stage tiles 0,1 (6 loads); vmcnt(3) -> tile 0 landed.
  STAGE(0, 0);
  STAGE(1, 1);
  WAIT_VM(3);
  __builtin_amdgcn_s_barrier();

#pragma unroll 1
  for (int kt = 0; kt < 60; kt += 3) {
    TILE(0, 2, kt + 0, 1, WAIT_VM(3));
    TILE(1, 0, kt + 1, 1, WAIT_VM(3));
    TILE(2, 1, kt + 2, 1, WAIT_VM(3));
  }
  // tail: tau 60 stages 62, tau 61 stages 63; drain 3 -> 0.
  TILE(0, 2, 60, 1, WAIT_VM(3));
  TILE(1, 0, 61, 1, WAIT_VM(3));
  TILE(2, 1, 62, 0, WAIT_VM(0));
  TILE(0, 2, 63, 0, (void)0);
#undef TILE
#undef STAGE

  // ---- epilogue: scatter into q | k | vT (layouts match rope_k / attn_k) ----
  // C row = m0 + wm*64 + mi*16 + quad*4 + r ; C col = n0 + wn*64 + ni*16 + l15
  const int which = n0 >> 11;  // 0=q 1=k 2=v (2048 % 256 == 0 -> block-uniform)
  const int bb = m0 >> 11, tt0 = m0 & 2047;
  if (which == 2) {
    u16* vbase = q3 + 16777216;
#pragma unroll
    for (int ni = 0; ni < 4; ni++) {
      const int gcol = (n0 & 2047) + wn * 64 + ni * 16 + l15;
      const int hh = gcol >> 7, di = gcol & 127;
      u16* vb = vbase + ((size_t)(bb * 16 + hh) * 128 + di) * 2048;
#pragma unroll
      for (int mi = 0; mi < 4; mi++) {
        const int tloc = tt0 + wm * 64 + mi * 16 + quad * 4;
        s16x4 st;
#pragma unroll
        for (int r = 0; r < 4; r++) st[r] = (short)f2bf(acc[mi][ni][r]);
        *(s16x4*)(vb + tloc) = st;  // 4 consecutive t -> 8B store
      }
    }
  } else {
    const float sc = (which == 0) ? 0.1275174f : 1.0f;  // 1/sqrt(128)*log2(e)
    u16* base = q3 + (size_t)which * 8388608;
#pragma unroll
    for (int ni = 0; ni < 4; ni++) {
      const int gcol = (n0 & 2047) + wn * 64 + ni * 16 + l15;
      const int hh = gcol >> 7, di = gcol & 127;
      u16* qb = base + ((size_t)(bb * 16 + hh) * 2048) * 128 + di;
#pragma unroll
      for (int mi = 0; mi < 4; mi++) {
        const int tloc = tt0 + wm * 64 + mi * 16 + quad * 4;
#pragma unroll
        for (int r = 0; r < 4; r++)
          qb[(size_t)(tloc + r) * 128] = f2bf(acc[mi][ni][r] * sc);
      }
    }
  }
}

// ---------------- BT GEMM (kept for the output projection), 32x32x16 MFMA --------
template <int EPI>
__global__ __launch_bounds__(256) void gemm_bt(const u16* __restrict__ A,
                                               const u16* __restrict__ B,
                                               int K, void* __restrict__ Cv, int N) {
  __shared__ __align__(16) u16 SMEM[8448];  // staging 16KB; EPI=1 epilogue f32[32][132]
  u16* As = SMEM;
  u16* Bs = SMEM + 4096;
  const int m0 = blockIdx.y * 128, n0 = blockIdx.x * 128;
  const int t = threadIdx.x, w = t >> 6, lane = t & 63;
  const int l31 = lane & 31, half = lane >> 5;
  const int rb = (w >> 1) * 64, cb = (w & 1) * 64;
  f32x16 acc[2][2] = {};
  const int rowS = w * 16 + (lane >> 2);                // staged row (0..63, +64 second)
  const int cS = ((lane & 3) - (rowS >> 1)) & 3;        // swizzled source chunk
  const u16* ag = A + (size_t)(m0 + rowS) * K + cS * 8;
  const u16* bg = B + (size_t)(n0 + rowS) * K + cS * 8;
  u16* al = As + w * 512 + lane * 8;  // lane-contiguous: base + lane*16B
  u16* bl = Bs + w * 512 + lane * 8;
  const size_t rowskip = (size_t)64 * K;
  const int p0 = ((0 * 2 + half + (l31 >> 1)) & 3) * 8;  // kh=0
  const int p1 = ((1 * 2 + half + (l31 >> 1)) & 3) * 8;  // kh=1
  for (int k0 = 0; k0 < K; k0 += 32) {
    __syncthreads();
    gld16(ag, al);
    gld16(ag + rowskip, al + 2048);
    gld16(bg, bl);
    gld16(bg + rowskip, bl + 2048);
    ag += 32;
    bg += 32;
    __syncthreads();
    short8 af[2][2], bfr[2][2];
#pragma unroll
    for (int mi = 0; mi < 2; mi++) {
      af[mi][0] = *(const short8*)&As[(rb + mi * 32 + l31) * 32 + p0];
      af[mi][1] = *(const short8*)&As[(rb + mi * 32 + l31) * 32 + p1];
    }
#pragma unroll
    for (int ni = 0; ni < 2; ni++) {
      bfr[ni][0] = *(const short8*)&Bs[(cb + ni * 32 + l31) * 32 + p0];
      bfr[ni][1] = *(const short8*)&Bs[(cb + ni * 32 + l31) * 32 + p1];
    }
#pragma unroll
    for (int kh = 0; kh < 2; kh++)
#pragma unroll
      for (int mi = 0; mi < 2; mi++)
#pragma unroll
        for (int ni = 0; ni < 2; ni++)
          acc[mi][ni] = mfma32(af[mi][kh], bfr[ni][kh], acc[mi][ni]);
  }

  if (EPI == 0) {
    const int which = n0 >> 11;
    const int hh = (n0 & 2047) >> 7;
    const int bb = m0 >> 11, tt0 = m0 & 2047;
    u16* q3 = (u16*)Cv;
    if (which == 2) {
      u16* vbase = q3 + 16777216 + ((size_t)(bb * 16 + hh) * 128) * 2048;
#pragma unroll
      for (int mi = 0; mi < 2; mi++)
#pragma unroll
        for (int ni = 0; ni < 2; ni++) {
          int di = cb + ni * 32 + l31;
          int trow = tt0 + rb + mi * 32 + half * 4;
#pragma unroll
          for (int rg2 = 0; rg2 < 4; rg2++) {
            s16x4 st;
#pragma unroll
            for (int j = 0; j < 4; j++) st[j] = (short)f2bf(acc[mi][ni][rg2 * 4 + j]);
            *(s16x4*)(vbase + (size_t)di * 2048 + trow + rg2 * 8) = st;
          }
        }
    } else {
      const float sc = (which == 0) ? 0.1275174f : 1.0f;
      u16* base = q3 + (size_t)which * 8388608 + ((size_t)(bb * 16 + hh) * 2048) * 128;
#pragma unroll
      for (int mi = 0; mi < 2; mi++)
#pragma unroll
        for (int ni = 0; ni < 2; ni++) {
          int di = cb + ni * 32 + l31;
          int trow = tt0 + rb + mi * 32 + half * 4;
#pragma unroll
          for (int reg = 0; reg < 16; reg++) {
            int tt = trow + (reg & 3) + 8 * (reg >> 2);
            base[(size_t)tt * 128 + di] = f2bf(acc[mi][ni][reg] * sc);
          }
        }
    }
  } else {
    float* Es = (float*)SMEM;  // [32][132]
    float* C = (float*)Cv;
#pragma unroll
    for (int r = 0; r < 4; r++) {
      __syncthreads();
      if ((w >> 1) == (r >> 1)) {
        const int mi = r & 1;
#pragma unroll
        for (int ni = 0; ni < 2; ni++) {
          int col = cb + ni * 32 + l31;
#pragma unroll
          for (int reg = 0; reg < 16; reg++) {
            int lrow = (reg & 3) + 8 * (reg >> 2) + half * 4;
            Es[lrow * 132 + col] = acc[mi][ni][reg];
          }
        }
      }
      __syncthreads();
#pragma unroll
      for (int it = 0; it < 4; it++) {
        int idx = it * 256 + t;
        int row = idx >> 5, ch = idx & 31;
        f32x4 vv = *(const f32x4*)&Es[row * 132 + ch * 4];
        *(f32x4*)&C[(size_t)(m0 + r * 32 + row) * N + n0 + ch * 4] = vv;
      }
    }
  }
}

// ---------------- RoPE in-place on q,k (heads 0..7 only) ----------------
__global__ __launch_bounds__(256) void rope_k(u16* __restrict__ q, u16* __restrict__ k,
                                              const float* __restrict__ cosT,
                                              const float* __restrict__ sinT) {
  int t = threadIdx.x;
  int row = blockIdx.x * 4 + (t >> 6);  // over (b, h<8, tpos)
  int i = t & 63;
  int b = row >> 14;
  int h = (row >> 11) & 7;
  int tp = row & 2047;
  size_t base = ((size_t)((b * 16 + h) * 2048 + tp)) * 128 + 2 * i;
  float c = cosT[tp * 64 + i], s = sinT[tp * 64 + i];
  {
    uint32_t u = *(uint32_t*)(q + base);
    float x0 = bf2f((u16)(u & 0xffff)), x1 = bf2f((u16)(u >> 16));
    float re = x0 * c - x1 * s, im = x0 * s + x1 * c;
    *(uint32_t*)(q + base) = (uint32_t)f2bf(re) | ((uint32_t)f2bf(im) << 16);
  }
  {
    uint32_t u = *(uint32_t*)(k + base);
    float x0 = bf2f((u16)(u & 0xffff)), x1 = bf2f((u16)(u >> 16));
    float re = x0 * c - x1 * s, im = x0 * s + x1 * c;
    *(uint32_t*)(k + base) = (uint32_t)f2bf(re) | ((uint32_t)f2bf(im) << 16);
  }
}

// ---------------- flash attention, S^T orientation ----------------
__global__ __launch_bounds__(256, 2) void attn_k(const u16* __restrict__ qh,
                                                 const u16* __restrict__ kh,
                                                 const u16* __restrict__ vTh,
                                                 u16* __restrict__ attno) {
  __shared__ __align__(16) u16 Ks[8192];  // 64 keys x 128 d, XOR-swizzled 16B chunks
  __shared__ __align__(16) u16 Vt[8192];  // 128 d x 64 keys, XOR-swizzled 16B chunks
  const int i = blockIdx.x;
  const int jj = i & 255, half = i >> 8;
  const int bh = jj >> 3, t8 = jj & 7;
  const int qt = half ? (15 - t8) : t8;
  const int q0 = qt * 128;
  const int t = threadIdx.x, w = t >> 6, lane = t & 63;
  const int quad = lane >> 4, l15 = lane & 15;
  const size_t bhoff = (size_t)bh * 262144;

  short8 qb[2][4];
  {
    const u16* qp = qh + bhoff + (size_t)(q0 + w * 32 + l15) * 128 + quad * 8;
#pragma unroll
    for (int qq = 0; qq < 2; qq++)
#pragma unroll
      for (int ks = 0; ks < 4; ks++)
        qb[qq][ks] = *(const short8*)(qp + qq * 2048 + ks * 32);
  }
  f32x4 of[2][8] = {};
  float mst[2] = {-1e30f, -1e30f}, lst[2] = {0.f, 0.f};
  const int nkt = 2 * qt + 2;
  const int wq0 = q0 + w * 32;

  for (int kt = 0; kt < nkt; kt++) {
    const int k0 = kt * 64;
    __syncthreads();
    {
#pragma unroll
      for (int it = 0; it < 4; it++) {  // K: 64 rows x 16 chunks
        int L = it * 256 + t;
        int key = L >> 4, c = L & 15;
        gld16(kh + bhoff + (size_t)(k0 + key) * 128 + ((c ^ (key & 15)) * 8),
              Ks + (size_t)L * 8);
      }
#pragma unroll
      for (int it = 0; it < 4; it++) {  // V^T: 128 rows x 8 chunks
        int L = it * 256 + t;
        int d = L >> 3, c = L & 7;
        gld16(vTh + bhoff + (size_t)d * 2048 + k0 + ((c ^ (d & 7)) * 8),
              Vt + (size_t)L * 8);
      }
    }
    __syncthreads();
    if (k0 <= wq0 + 31) {
      f32x4 sacc[2][4];
#pragma unroll
      for (int qq = 0; qq < 2; qq++)
#pragma unroll
        for (int kk = 0; kk < 4; kk++) sacc[qq][kk] = (f32x4){0.f, 0.f, 0.f, 0.f};
#pragma unroll
      for (int kk = 0; kk < 4; kk++) {
        short8 kf[4];
#pragma unroll
        for (int ks = 0; ks < 4; ks++)
          kf[ks] = *(const short8*)&Ks[(kk * 16 + l15) * 128 + ((ks * 4 + quad) ^ l15) * 8];
#pragma unroll
        for (int qq = 0; qq < 2; qq++)
#pragma unroll
          for (int ks = 0; ks < 4; ks++)
            sacc[qq][kk] = mfma16(kf[ks], qb[qq][ks], sacc[qq][kk]);
      }
      const bool needmask = (k0 + 63 > wq0);
      s16x4 pf[2][4];
      float alpha[2];
#pragma unroll
      for (int qq = 0; qq < 2; qq++) {
        const int qg = wq0 + qq * 16 + l15;
        if (needmask) {
#pragma unroll
          for (int kk = 0; kk < 4; kk++)
#pragma unroll
            for (int rg = 0; rg < 4; rg++)
              if (k0 + kk * 16 + quad * 4 + rg > qg) sacc[qq][kk][rg] = -1e30f;
        }
        float pm = -1e30f;
#pragma unroll
        for (int kk = 0; kk < 4; kk++)
#pragma unroll
          for (int rg = 0; rg < 4; rg++) pm = fmaxf(pm, sacc[qq][kk][rg]);
        pm = fmaxf(pm, __shfl_xor(pm, 16));
        pm = fmaxf(pm, __shfl_xor(pm, 32));
        float mnew = fmaxf(mst[qq], pm);
        alpha[qq] = exp2a(mst[qq] - mnew);
        mst[qq] = mnew;
        float ps = 0.f;
#pragma unroll
        for (int kk = 0; kk < 4; kk++) {
          float e0 = exp2a(sacc[qq][kk][0] - mnew);
          float e1 = exp2a(sacc[qq][kk][1] - mnew);
          float e2 = exp2a(sacc[qq][kk][2] - mnew);
          float e3 = exp2a(sacc[qq][kk][3] - mnew);
          ps += (e0 + e1) + (e2 + e3);
          pf[qq][kk][0] = (short)f2bf(e0);
          pf[qq][kk][1] = (short)f2bf(e1);
          pf[qq][kk][2] = (short)f2bf(e2);
          pf[qq][kk][3] = (short)f2bf(e3);
        }
        ps += __shfl_xor(ps, 16);
        ps += __shfl_xor(ps, 32);
        lst[qq] = lst[qq] * alpha[qq] + ps;
      }
#pragma unroll
      for (int qq = 0; qq < 2; qq++) {
        if (!__all(alpha[qq] == 1.0f)) {
          float a = alpha[qq];
#pragma unroll
          for (int df = 0; df < 8; df++) of[qq][df] *= a;
        }
      }
#pragma unroll
      for (int df = 0; df < 8; df++) {
        s16x4 vf[4];
#pragma unroll
        for (int kk = 0; kk < 4; kk++)
          vf[kk] = *(const s16x4*)&Vt[(df * 16 + l15) * 64 +
                                      ((kk * 2 + (quad >> 1)) ^ (l15 & 7)) * 8 +
                                      (quad & 1) * 4];
#pragma unroll
        for (int qq = 0; qq < 2; qq++)
#pragma unroll
          for (int kk = 0; kk < 4; kk++)
            of[qq][df] = mfma16k16(vf[kk], pf[qq][kk], of[qq][df]);
      }
    }
  }
  const int b = bh >> 4, h = bh & 15;
#pragma unroll
  for (int qq = 0; qq < 2; qq++) {
    float linv = 1.0f / lst[qq];
    const size_t row = (size_t)(b * 2048 + q0 + w * 32 + qq * 16 + l15);
#pragma unroll
    for (int df = 0; df < 8; df++) {
      s16x4 o;
#pragma unroll
      for (int rg = 0; rg < 4; rg++) o[rg] = (short)f2bf(of[qq][df][rg] * linv);
      *(s16x4*)(attno + row * 2048 + h * 128 + df * 16 + quad * 4) = o;
    }
  }
}

extern "C" void kernel_launch(void* const* d_in, const int* in_sizes, int n_in,
                              void* d_out, int out_size, void* d_ws, size_t ws_size,
                              hipStream_t stream) {
  const float* x = (const float*)d_in[0];
  const float* Wqkv = (const float*)d_in[1];
  const float* Wout = (const float*)d_in[2];
  const float* cosT = (const float*)d_in[3];
  const float* sinT = (const float*)d_in[4];
  float* out = (float*)d_out;
  char* ws = (char*)d_ws;
  // workspace (96 MiB), lifetime-based reuse:
  //   [0,        50331648)  qkvh: q | k | vT (vT = per-head transposed v)
  //   [50331648, 58720256)  woutb (persists to gemm2)
  //   [58720256, 75497472)  xb (dead after gemm1)
  //   [75497472,100663296)  wqkvb (dead after gemm1) -> reused as attno
  u16* qkvh = (u16*)(ws + 0);
  u16* woutb = (u16*)(ws + 50331648);
  u16* xb = (u16*)(ws + 58720256);
  u16* wqkvb = (u16*)(ws + 75497472);
  u16* attno = wqkvb;

  cvt_all<<<12288, 256, 0, stream>>>(x, Wqkv, Wout, xb, wqkvb, woutb);
  gemm_qkv<<<768, 512, 0, stream>>>(xb, wqkvb, qkvh);
  rope_k<<<8192, 256, 0, stream>>>(qkvh, qkvh + 8388608, cosT, sinT);
  attn_k<<<512, 256, 0, stream>>>(qkvh, qkvh + 8388608, qkvh + 16777216, attno);
  gemm_bt<1><<<dim3(16, 32), 256, 0, stream>>>(attno, woutb, 2048, (void*)out, 2048);
}

// Round 6
// 394.876 us; speedup vs baseline: 1.0352x; 1.0009x over previous
//
#include <hip/hip_runtime.h>
#include <stdint.h>

typedef unsigned short u16;
typedef __attribute__((ext_vector_type(8))) short short8;
typedef __attribute__((ext_vector_type(4))) short s16x4;
typedef __attribute__((ext_vector_type(4))) float f32x4;
typedef __attribute__((ext_vector_type(16))) float f32x16;

__device__ __forceinline__ u16 f2bf(float f) {
  uint32_t x = __float_as_uint(f);
  x += 0x7fff + ((x >> 16) & 1);
  return (u16)(x >> 16);
}
__device__ __forceinline__ float bf2f(u16 u) {
  return __uint_as_float(((uint32_t)u) << 16);
}
__device__ __forceinline__ f32x4 mfma16(short8 a, short8 b, f32x4 c) {
  return __builtin_amdgcn_mfma_f32_16x16x32_bf16(a, b, c, 0, 0, 0);
}
__device__ __forceinline__ f32x16 mfma32(short8 a, short8 b, f32x16 c) {
  return __builtin_amdgcn_mfma_f32_32x32x16_bf16(a, b, c, 0, 0, 0);
}
__device__ __forceinline__ f32x4 mfma16k16(s16x4 a, s16x4 b, f32x4 c) {
  return __builtin_amdgcn_mfma_f32_16x16x16bf16_1k(a, b, c, 0, 0, 0);
}
__device__ __forceinline__ void gld16(const u16* g, u16* l) {
  __builtin_amdgcn_global_load_lds(
      (const __attribute__((address_space(1))) unsigned int*)g,
      (__attribute__((address_space(3))) unsigned int*)l, 16, 0, 0);
}
__device__ __forceinline__ float exp2a(float x) {  // raw v_exp_f32 (2^x)
  float r;
  asm("v_exp_f32 %0, %1" : "=v"(r) : "v"(x));
  return r;
}

#define WAIT_VM(n) asm volatile("s_waitcnt vmcnt(" #n ")" ::: "memory")

// ---------------- fused fp32 -> bf16 conversion (x | Wqkv | Wout) ----------------
__global__ __launch_bounds__(256) void cvt_all(const float* __restrict__ x,
                                               const float* __restrict__ wqkv,
                                               const float* __restrict__ wout,
                                               u16* __restrict__ xb,
                                               u16* __restrict__ wqkvb,
                                               u16* __restrict__ woutb) {
  long i = ((long)blockIdx.x * 256 + threadIdx.x) * 8;
  const float* s;
  u16* d;
  long off;
  if (i < 8388608) {
    s = x; d = xb; off = i;
  } else if (i < 20971520) {
    s = wqkv; d = wqkvb; off = i - 8388608;
  } else {
    s = wout; d = woutb; off = i - 20971520;
  }
  f32x4 a = *(const f32x4*)(s + off);
  f32x4 b = *(const f32x4*)(s + off + 4);
  short8 o;
#pragma unroll
  for (int j = 0; j < 4; j++) {
    o[j] = (short)f2bf(a[j]);
    o[j + 4] = (short)f2bf(b[j]);
  }
  *(short8*)(d + off) = o;
}

// ---------------- QKV GEMM: 128x256 tile, 8 waves, BK=32, 3-ring LDS ----------------
// (validated round-5: 128 us, 0 bank conflicts, 2 blocks/CU, occupancy 34%)
// 72 KiB LDS -> 2 blocks/CU; co-resident blocks provide the LDS/MFMA pipe overlap
// (m114) that no single-block source schedule achieved (rounds 2-4 all ~158 us).
// Counted vmcnt: 3 loads/tile/thread; steady wait vmcnt(3); drain at tail only.
// LDS chunk swizzle: stored 16B chunk at row r, position p holds global chunk
// (p - (r>>1)) & 3; fragment reads use position ((quad + (l15>>1)) & 3).
__global__ __launch_bounds__(512, 4) void gemm_qkv(const u16* __restrict__ A,
                                                   const u16* __restrict__ Bw,
                                                   u16* __restrict__ q3) {
  __shared__ __align__(16) u16 SA[12288];  // 3 rings x [128 rows][32 k] = 24 KiB
  __shared__ __align__(16) u16 SB[24576];  // 3 rings x [256 rows][32 k] = 48 KiB
  // bijective XCD swizzle: 768 = 8 XCDs x 96; each XCD owns 3 n-panels x 32 m
  const int id = blockIdx.x;
  const int swz = (id & 7) * 96 + (id >> 3);
  const int by = swz & 31, bx = swz >> 5;
  const int m0 = by * 128, n0 = bx * 256;
  const int t = threadIdx.x, w = t >> 6, lane = t & 63;
  const int quad = lane >> 4, l15 = lane & 15;
  const int wm = w >> 2, wn = w & 3;  // 2 x 4 wave grid; per-wave C = 64 x 64
  const int rS = t >> 2, pS = t & 3;
  const int cS = (pS - (rS >> 1)) & 3;
  const size_t arowA = (size_t)(m0 + rS) * 2048 + cS * 8;
  const size_t arowB = (size_t)(n0 + rS) * 2048 + cS * 8;

  f32x4 acc[4][4] = {};  // 64 VGPR
  const int pq = ((quad + (l15 >> 1)) & 3) * 8;

#define STAGE(KT, RS_)                                   \
  {                                                      \
    const u16* ga_ = A + arowA + (size_t)(KT) * 32;      \
    gld16(ga_, SA + (RS_)*4096 + t * 8);                 \
    const u16* gb_ = Bw + arowB + (size_t)(KT) * 32;     \
    u16* lb_ = SB + (RS_)*8192 + t * 8;                  \
    gld16(gb_, lb_);                                     \
    gld16(gb_ + (size_t)128 * 2048, lb_ + 4096);         \
  }

#define TILE(RC, RSS, TAU, DO_STAGE, WAIT)                                    \
  {                                                                           \
    const u16* Sa_ = SA + (RC)*4096;                                          \
    const u16* Sb_ = SB + (RC)*8192;                                          \
    if (DO_STAGE) STAGE((TAU) + 2, RSS);                                      \
    short8 af[4], bf[4];                                                      \
    _Pragma("unroll") for (int i = 0; i < 4; i++)                             \
        af[i] = *(const short8*)&Sa_[(wm * 64 + i * 16 + l15) * 32 + pq];     \
    _Pragma("unroll") for (int n = 0; n < 4; n++)                             \
        bf[n] = *(const short8*)&Sb_[(wn * 64 + n * 16 + l15) * 32 + pq];     \
    __builtin_amdgcn_s_setprio(1);                                            \
    _Pragma("unroll") for (int mi = 0; mi < 4; mi++)                          \
      _Pragma("unroll") for (int ni = 0; ni < 4; ni++)                        \
          acc[mi][ni] = mfma16(af[mi], bf[ni], acc[mi][ni]);                  \
    __builtin_amdgcn_s_setprio(0);                                            \
    WAIT;                                                                     \
    __builtin_amdgcn_s_barrier();                                             \
  }

  STAGE(0, 0);
  STAGE(1, 1);
  WAIT_VM(3);
  __builtin_amdgcn_s_barrier();

#pragma unroll 1
  for (int kt = 0; kt < 60; kt += 3) {
    TILE(0, 2, kt + 0, 1, WAIT_VM(3));
    TILE(1, 0, kt + 1, 1, WAIT_VM(3));
    TILE(2, 1, kt + 2, 1, WAIT_VM(3));
  }
  TILE(0, 2, 60, 1, WAIT_VM(3));
  TILE(1, 0, 61, 1, WAIT_VM(3));
  TILE(2, 1, 62, 0, WAIT_VM(0));
  TILE(0, 2, 63, 0, (void)0);
#undef TILE
#undef STAGE

  // ---- epilogue: scatter into q | k | vT (layouts match rope_k / attn_k) ----
  const int which = n0 >> 11;  // 0=q 1=k 2=v (2048 % 256 == 0 -> block-uniform)
  const int bb = m0 >> 11, tt0 = m0 & 2047;
  if (which == 2) {
    u16* vbase = q3 + 16777216;
#pragma unroll
    for (int ni = 0; ni < 4; ni++) {
      const int gcol = (n0 & 2047) + wn * 64 + ni * 16 + l15;
      const int hh = gcol >> 7, di = gcol & 127;
      u16* vb = vbase + ((size_t)(bb * 16 + hh) * 128 + di) * 2048;
#pragma unroll
      for (int mi = 0; mi < 4; mi++) {
        const int tloc = tt0 + wm * 64 + mi * 16 + quad * 4;
        s16x4 st;
#pragma unroll
        for (int r = 0; r < 4; r++) st[r] = (short)f2bf(acc[mi][ni][r]);
        *(s16x4*)(vb + tloc) = st;  // 4 consecutive t -> 8B store
      }
    }
  } else {
    const float sc = (which == 0) ? 0.1275174f : 1.0f;  // 1/sqrt(128)*log2(e)
    u16* base = q3 + (size_t)which * 8388608;
#pragma unroll
    for (int ni = 0; ni < 4; ni++) {
      const int gcol = (n0 & 2047) + wn * 64 + ni * 16 + l15;
      const int hh = gcol >> 7, di = gcol & 127;
      u16* qb = base + ((size_t)(bb * 16 + hh) * 2048) * 128 + di;
#pragma unroll
      for (int mi = 0; mi < 4; mi++) {
        const int tloc = tt0 + wm * 64 + mi * 16 + quad * 4;
#pragma unroll
        for (int r = 0; r < 4; r++)
          qb[(size_t)(tloc + r) * 128] = f2bf(acc[mi][ni][r] * sc);
      }
    }
  }
}

// ---------------- BT GEMM (kept for the output projection), 32x32x16 MFMA --------
template <int EPI>
__global__ __launch_bounds__(256) void gemm_bt(const u16* __restrict__ A,
                                               const u16* __restrict__ B,
                                               int K, void* __restrict__ Cv, int N) {
  __shared__ __align__(16) u16 SMEM[8448];  // staging 16KB; EPI=1 epilogue f32[32][132]
  u16* As = SMEM;
  u16* Bs = SMEM + 4096;
  const int m0 = blockIdx.y * 128, n0 = blockIdx.x * 128;
  const int t = threadIdx.x, w = t >> 6, lane = t & 63;
  const int l31 = lane & 31, half = lane >> 5;
  const int rb = (w >> 1) * 64, cb = (w & 1) * 64;
  f32x16 acc[2][2] = {};
  const int rowS = w * 16 + (lane >> 2);                // staged row (0..63, +64 second)
  const int cS = ((lane & 3) - (rowS >> 1)) & 3;        // swizzled source chunk
  const u16* ag = A + (size_t)(m0 + rowS) * K + cS * 8;
  const u16* bg = B + (size_t)(n0 + rowS) * K + cS * 8;
  u16* al = As + w * 512 + lane * 8;  // lane-contiguous: base + lane*16B
  u16* bl = Bs + w * 512 + lane * 8;
  const size_t rowskip = (size_t)64 * K;
  const int p0 = ((0 * 2 + half + (l31 >> 1)) & 3) * 8;  // kh=0
  const int p1 = ((1 * 2 + half + (l31 >> 1)) & 3) * 8;  // kh=1
  for (int k0 = 0; k0 < K; k0 += 32) {
    __syncthreads();
    gld16(ag, al);
    gld16(ag + rowskip, al + 2048);
    gld16(bg, bl);
    gld16(bg + rowskip, bl + 2048);
    ag += 32;
    bg += 32;
    __syncthreads();
    short8 af[2][2], bfr[2][2];
#pragma unroll
    for (int mi = 0; mi < 2; mi++) {
      af[mi][0] = *(const short8*)&As[(rb + mi * 32 + l31) * 32 + p0];
      af[mi][1] = *(const short8*)&As[(rb + mi * 32 + l31) * 32 + p1];
    }
#pragma unroll
    for (int ni = 0; ni < 2; ni++) {
      bfr[ni][0] = *(const short8*)&Bs[(cb + ni * 32 + l31) * 32 + p0];
      bfr[ni][1] = *(const short8*)&Bs[(cb + ni * 32 + l31) * 32 + p1];
    }
#pragma unroll
    for (int kh = 0; kh < 2; kh++)
#pragma unroll
      for (int mi = 0; mi < 2; mi++)
#pragma unroll
        for (int ni = 0; ni < 2; ni++)
          acc[mi][ni] = mfma32(af[mi][kh], bfr[ni][kh], acc[mi][ni]);
  }

  if (EPI == 0) {
    const int which = n0 >> 11;
    const int hh = (n0 & 2047) >> 7;
    const int bb = m0 >> 11, tt0 = m0 & 2047;
    u16* q3 = (u16*)Cv;
    if (which == 2) {
      u16* vbase = q3 + 16777216 + ((size_t)(bb * 16 + hh) * 128) * 2048;
#pragma unroll
      for (int mi = 0; mi < 2; mi++)
#pragma unroll
        for (int ni = 0; ni < 2; ni++) {
          int di = cb + ni * 32 + l31;
          int trow = tt0 + rb + mi * 32 + half * 4;
#pragma unroll
          for (int rg2 = 0; rg2 < 4; rg2++) {
            s16x4 st;
#pragma unroll
            for (int j = 0; j < 4; j++) st[j] = (short)f2bf(acc[mi][ni][rg2 * 4 + j]);
            *(s16x4*)(vbase + (size_t)di * 2048 + trow + rg2 * 8) = st;
          }
        }
    } else {
      const float sc = (which == 0) ? 0.1275174f : 1.0f;
      u16* base = q3 + (size_t)which * 8388608 + ((size_t)(bb * 16 + hh) * 2048) * 128;
#pragma unroll
      for (int mi = 0; mi < 2; mi++)
#pragma unroll
        for (int ni = 0; ni < 2; ni++) {
          int di = cb + ni * 32 + l31;
          int trow = tt0 + rb + mi * 32 + half * 4;
#pragma unroll
          for (int reg = 0; reg < 16; reg++) {
            int tt = trow + (reg & 3) + 8 * (reg >> 2);
            base[(size_t)tt * 128 + di] = f2bf(acc[mi][ni][reg] * sc);
          }
        }
    }
  } else {
    float* Es = (float*)SMEM;  // [32][132]
    float* C = (float*)Cv;
#pragma unroll
    for (int r = 0; r < 4; r++) {
      __syncthreads();
      if ((w >> 1) == (r >> 1)) {
        const int mi = r & 1;
#pragma unroll
        for (int ni = 0; ni < 2; ni++) {
          int col = cb + ni * 32 + l31;
#pragma unroll
          for (int reg = 0; reg < 16; reg++) {
            int lrow = (reg & 3) + 8 * (reg >> 2) + half * 4;
            Es[lrow * 132 + col] = acc[mi][ni][reg];
          }
        }
      }
      __syncthreads();
#pragma unroll
      for (int it = 0; it < 4; it++) {
        int idx = it * 256 + t;
        int row = idx >> 5, ch = idx & 31;
        f32x4 vv = *(const f32x4*)&Es[row * 132 + ch * 4];
        *(f32x4*)&C[(size_t)(m0 + r * 32 + row) * N + n0 + ch * 4] = vv;
      }
    }
  }
}

// ---------------- RoPE in-place on q,k (heads 0..7 only) ----------------
__global__ __launch_bounds__(256) void rope_k(u16* __restrict__ q, u16* __restrict__ k,
                                              const float* __restrict__ cosT,
                                              const float* __restrict__ sinT) {
  int t = threadIdx.x;
  int row = blockIdx.x * 4 + (t >> 6);  // over (b, h<8, tpos)
  int i = t & 63;
  int b = row >> 14;
  int h = (row >> 11) & 7;
  int tp = row & 2047;
  size_t base = ((size_t)((b * 16 + h) * 2048 + tp)) * 128 + 2 * i;
  float c = cosT[tp * 64 + i], s = sinT[tp * 64 + i];
  {
    uint32_t u = *(uint32_t*)(q + base);
    float x0 = bf2f((u16)(u & 0xffff)), x1 = bf2f((u16)(u >> 16));
    float re = x0 * c - x1 * s, im = x0 * s + x1 * c;
    *(uint32_t*)(q + base) = (uint32_t)f2bf(re) | ((uint32_t)f2bf(im) << 16);
  }
  {
    uint32_t u = *(uint32_t*)(k + base);
    float x0 = bf2f((u16)(u & 0xffff)), x1 = bf2f((u16)(u >> 16));
    float re = x0 * c - x1 * s, im = x0 * s + x1 * c;
    *(uint32_t*)(k + base) = (uint32_t)f2bf(re) | ((uint32_t)f2bf(im) << 16);
  }
}

// ---------------- flash attention, S^T orientation, double-buffered K/V ----------
// Round-6 change: K/V DOUBLE-BUFFER + counted vmcnt. The old per-tile
// __syncthreads() after global_load_lds forced a compiler vmcnt(0) drain -- full
// HBM/L2 latency exposed every tile with only 8 waves/CU to hide it (attn was
// ~170 us vs ~25 us compute floor). Now: raw s_barrier + explicit vmcnt(8):
//   barrier (all waves done reading buf^1) -> stage kt+1 into buf^1 ->
//   vmcnt(8) (kt's 8 loads landed; kt+1's 8 stay in flight) -> barrier -> compute.
// Ring safety mirrors the HW-validated gemm_qkv argument: reads of a buffer are
// lgkm-consumed before the barrier that precedes the overwriting stage's issue.
// T5 setprio around QK^T and PV MFMA clusters (m191: +4-7% attn).
__global__ __launch_bounds__(256, 2) void attn_k(const u16* __restrict__ qh,
                                                 const u16* __restrict__ kh,
                                                 const u16* __restrict__ vTh,
                                                 u16* __restrict__ attno) {
  __shared__ __align__(16) u16 Ks[16384];  // 2 bufs x (64 keys x 128 d), XOR-swizzled
  __shared__ __align__(16) u16 Vt[16384];  // 2 bufs x (128 d x 64 keys), XOR-swizzled
  const int i = blockIdx.x;
  const int jj = i & 255, half = i >> 8;
  const int bh = jj >> 3, t8 = jj & 7;
  const int qt = half ? (15 - t8) : t8;
  const int q0 = qt * 128;
  const int t = threadIdx.x, w = t >> 6, lane = t & 63;
  const int quad = lane >> 4, l15 = lane & 15;
  const size_t bhoff = (size_t)bh * 262144;

  short8 qb[2][4];
  {
    const u16* qp = qh + bhoff + (size_t)(q0 + w * 32 + l15) * 128 + quad * 8;
#pragma unroll
    for (int qq = 0; qq < 2; qq++)
#pragma unroll
      for (int ks = 0; ks < 4; ks++)
        qb[qq][ks] = *(const short8*)(qp + qq * 2048 + ks * 32);
  }
  f32x4 of[2][8] = {};
  float mst[2] = {-1e30f, -1e30f}, lst[2] = {0.f, 0.f};
  const int nkt = 2 * qt + 2;
  const int wq0 = q0 + w * 32;

#define ASTAGE(KT, BUF)                                                        \
  {                                                                            \
    const int k0_ = (KT) * 64;                                                 \
    _Pragma("unroll") for (int it = 0; it < 4; it++) {                         \
      int L = it * 256 + t;                                                    \
      int key = L >> 4, c = L & 15;                                            \
      gld16(kh + bhoff + (size_t)(k0_ + key) * 128 + ((c ^ (key & 15)) * 8),   \
            Ks + (BUF)*8192 + (size_t)L * 8);                                  \
    }                                                                          \
    _Pragma("unroll") for (int it = 0; it < 4; it++) {                         \
      int L = it * 256 + t;                                                    \
      int d = L >> 3, c = L & 7;                                               \
      gld16(vTh + bhoff + (size_t)d * 2048 + k0_ + ((c ^ (d & 7)) * 8),        \
            Vt + (BUF)*8192 + (size_t)L * 8);                                  \
    }                                                                          \
  }

  ASTAGE(0, 0);
#pragma unroll 1
  for (int kt = 0; kt < nkt; kt++) {
    const int buf = kt & 1;
    const int k0 = kt * 64;
    __builtin_amdgcn_s_barrier();  // all waves done reading buf^1 (tile kt-1)
    if (kt + 1 < nkt) {
      ASTAGE(kt + 1, buf ^ 1);
      WAIT_VM(8);  // tile kt's 8 loads landed; kt+1's 8 stay in flight
    } else {
      WAIT_VM(0);
    }
    __builtin_amdgcn_s_barrier();  // tile kt visible to all waves
    if (k0 <= wq0 + 31) {
      const u16* Kb = Ks + buf * 8192;
      const u16* Vb = Vt + buf * 8192;
      f32x4 sacc[2][4];
#pragma unroll
      for (int qq = 0; qq < 2; qq++)
#pragma unroll
        for (int kk = 0; kk < 4; kk++) sacc[qq][kk] = (f32x4){0.f, 0.f, 0.f, 0.f};
#pragma unroll
      for (int kk = 0; kk < 4; kk++) {
        short8 kf[4];
#pragma unroll
        for (int ks = 0; ks < 4; ks++)
          kf[ks] = *(const short8*)&Kb[(kk * 16 + l15) * 128 + ((ks * 4 + quad) ^ l15) * 8];
        __builtin_amdgcn_s_setprio(1);
#pragma unroll
        for (int qq = 0; qq < 2; qq++)
#pragma unroll
          for (int ks = 0; ks < 4; ks++)
            sacc[qq][kk] = mfma16(kf[ks], qb[qq][ks], sacc[qq][kk]);
        __builtin_amdgcn_s_setprio(0);
      }
      const bool needmask = (k0 + 63 > wq0);
      s16x4 pf[2][4];
      float alpha[2];
#pragma unroll
      for (int qq = 0; qq < 2; qq++) {
        const int qg = wq0 + qq * 16 + l15;
        if (needmask) {
#pragma unroll
          for (int kk = 0; kk < 4; kk++)
#pragma unroll
            for (int rg = 0; rg < 4; rg++)
              if (k0 + kk * 16 + quad * 4 + rg > qg) sacc[qq][kk][rg] = -1e30f;
        }
        float pm = -1e30f;
#pragma unroll
        for (int kk = 0; kk < 4; kk++)
#pragma unroll
          for (int rg = 0; rg < 4; rg++) pm = fmaxf(pm, sacc[qq][kk][rg]);
        pm = fmaxf(pm, __shfl_xor(pm, 16));
        pm = fmaxf(pm, __shfl_xor(pm, 32));
        float mnew = fmaxf(mst[qq], pm);
        alpha[qq] = exp2a(mst[qq] - mnew);
        mst[qq] = mnew;
        float ps = 0.f;
#pragma unroll
        for (int kk = 0; kk < 4; kk++) {
          float e0 = exp2a(sacc[qq][kk][0] - mnew);
          float e1 = exp2a(sacc[qq][kk][1] - mnew);
          float e2 = exp2a(sacc[qq][kk][2] - mnew);
          float e3 = exp2a(sacc[qq][kk][3] - mnew);
          ps += (e0 + e1) + (e2 + e3);
          pf[qq][kk][0] = (short)f2bf(e0);
          pf[qq][kk][1] = (short)f2bf(e1);
          pf[qq][kk][2] = (short)f2bf(e2);
          pf[qq][kk][3] = (short)f2bf(e3);
        }
        ps += __shfl_xor(ps, 16);
        ps += __shfl_xor(ps, 32);
        lst[qq] = lst[qq] * alpha[qq] + ps;
      }
#pragma unroll
      for (int qq = 0; qq < 2; qq++) {
        if (!__all(alpha[qq] == 1.0f)) {
          float a = alpha[qq];
#pragma unroll
          for (int df = 0; df < 8; df++) of[qq][df] *= a;
        }
      }
#pragma unroll
      for (int df = 0; df < 8; df++) {
        s16x4 vf[4];
#pragma unroll
        for (int kk = 0; kk < 4; kk++)
          vf[kk] = *(const s16x4*)&Vb[(df * 16 + l15) * 64 +
                                      ((kk * 2 + (quad >> 1)) ^ (l15 & 7)) * 8 +
                                      (quad & 1) * 4];
        __builtin_amdgcn_s_setprio(1);
#pragma unroll
        for (int qq = 0; qq < 2; qq++)
#pragma unroll
          for (int kk = 0; kk < 4; kk++)
            of[qq][df] = mfma16k16(vf[kk], pf[qq][kk], of[qq][df]);
        __builtin_amdgcn_s_setprio(0);
      }
    }
  }
#undef ASTAGE
  const int b = bh >> 4, h = bh & 15;
#pragma unroll
  for (int qq = 0; qq < 2; qq++) {
    float linv = 1.0f / lst[qq];
    const size_t row = (size_t)(b * 2048 + q0 + w * 32 + qq * 16 + l15);
#pragma unroll
    for (int df = 0; df < 8; df++) {
      s16x4 o;
#pragma unroll
      for (int rg = 0; rg < 4; rg++) o[rg] = (short)f2bf(of[qq][df][rg] * linv);
      *(s16x4*)(attno + row * 2048 + h * 128 + df * 16 + quad * 4) = o;
    }
  }
}

extern "C" void kernel_launch(void* const* d_in, const int* in_sizes, int n_in,
                              void* d_out, int out_size, void* d_ws, size_t ws_size,
                              hipStream_t stream) {
  const float* x = (const float*)d_in[0];
  const float* Wqkv = (const float*)d_in[1];
  const float* Wout = (const float*)d_in[2];
  const float* cosT = (const float*)d_in[3];
  const float* sinT = (const float*)d_in[4];
  float* out = (float*)d_out;
  char* ws = (char*)d_ws;
  // workspace (96 MiB), lifetime-based reuse:
  //   [0,        50331648)  qkvh: q | k | vT (vT = per-head transposed v)
  //   [50331648, 58720256)  woutb (persists to gemm2)
  //   [58720256, 75497472)  xb (dead after gemm1)
  //   [75497472,100663296)  wqkvb (dead after gemm1) -> reused as attno
  u16* qkvh = (u16*)(ws + 0);
  u16* woutb = (u16*)(ws + 50331648);
  u16* xb = (u16*)(ws + 58720256);
  u16* wqkvb = (u16*)(ws + 75497472);
  u16* attno = wqkvb;

  cvt_all<<<12288, 256, 0, stream>>>(x, Wqkv, Wout, xb, wqkvb, woutb);
  gemm_qkv<<<768, 512, 0, stream>>>(xb, wqkvb, qkvh);
  rope_k<<<8192, 256, 0, stream>>>(qkvh, qkvh + 8388608, cosT, sinT);
  attn_k<<<512, 256, 0, stream>>>(qkvh, qkvh + 8388608, qkvh + 16777216, attno);
  gemm_bt<1><<<dim3(16, 32), 256, 0, stream>>>(attno, woutb, 2048, (void*)out, 2048);
}

// Round 7
// 390.375 us; speedup vs baseline: 1.0471x; 1.0115x over previous
//
#include <hip/hip_runtime.h>
#include <stdint.h>

typedef unsigned short u16;
typedef __attribute__((ext_vector_type(8))) short short8;
typedef __attribute__((ext_vector_type(4))) short s16x4;
typedef __attribute__((ext_vector_type(4))) float f32x4;
typedef __attribute__((ext_vector_type(16))) float f32x16;

__device__ __forceinline__ u16 f2bf(float f) {
  uint32_t x = __float_as_uint(f);
  x += 0x7fff + ((x >> 16) & 1);
  return (u16)(x >> 16);
}
__device__ __forceinline__ float bf2f(u16 u) {
  return __uint_as_float(((uint32_t)u) << 16);
}
__device__ __forceinline__ f32x4 mfma16(short8 a, short8 b, f32x4 c) {
  return __builtin_amdgcn_mfma_f32_16x16x32_bf16(a, b, c, 0, 0, 0);
}
__device__ __forceinline__ f32x16 mfma32(short8 a, short8 b, f32x16 c) {
  return __builtin_amdgcn_mfma_f32_32x32x16_bf16(a, b, c, 0, 0, 0);
}
__device__ __forceinline__ f32x4 mfma16k16(s16x4 a, s16x4 b, f32x4 c) {
  return __builtin_amdgcn_mfma_f32_16x16x16bf16_1k(a, b, c, 0, 0, 0);
}
__device__ __forceinline__ void gld16(const u16* g, u16* l) {
  __builtin_amdgcn_global_load_lds(
      (const __attribute__((address_space(1))) unsigned int*)g,
      (__attribute__((address_space(3))) unsigned int*)l, 16, 0, 0);
}
__device__ __forceinline__ float exp2a(float x) {  // raw v_exp_f32 (2^x)
  float r;
  asm("v_exp_f32 %0, %1" : "=v"(r) : "v"(x));
  return r;
}

#define WAIT_VM(n) asm volatile("s_waitcnt vmcnt(" #n ")" ::: "memory")

// ---------------- fused fp32 -> bf16 conversion (x | Wqkv | Wout) ----------------
__global__ __launch_bounds__(256) void cvt_all(const float* __restrict__ x,
                                               const float* __restrict__ wqkv,
                                               const float* __restrict__ wout,
                                               u16* __restrict__ xb,
                                               u16* __restrict__ wqkvb,
                                               u16* __restrict__ woutb) {
  long i = ((long)blockIdx.x * 256 + threadIdx.x) * 8;
  const float* s;
  u16* d;
  long off;
  if (i < 8388608) {
    s = x; d = xb; off = i;
  } else if (i < 20971520) {
    s = wqkv; d = wqkvb; off = i - 8388608;
  } else {
    s = wout; d = woutb; off = i - 20971520;
  }
  f32x4 a = *(const f32x4*)(s + off);
  f32x4 b = *(const f32x4*)(s + off + 4);
  short8 o;
#pragma unroll
  for (int j = 0; j < 4; j++) {
    o[j] = (short)f2bf(a[j]);
    o[j + 4] = (short)f2bf(b[j]);
  }
  *(short8*)(d + off) = o;
}

// ---------------- QKV GEMM: 128x192 tile, 8 waves, BK=32, 3-ring LDS ----------------
// C = A(4096x2048) * B(6144x2048)^T, bf16 BT layout. K = 2048 -> 64 K-tiles.
// Round-7 change: EXACT-RESIDENCY GRID. Round-5/6 model (validated vs measured
// 128 us): LDS pipe ~100 B/cyc/CU is binding with 2 blocks/CU; grid 768 at
// 2-resident capacity 512 ran 1.5 rounds -- the 256-block tail round executes in
// 1-block/CU SERIAL mode (2900 cyc/tile, rounds 2-4) and alone costs ~77 us.
// Fix: tile 128x192 -> grid 32x32 = 1024 blocks = EXACTLY 2.0 rounds of 512:
// every CU holds 2 co-resident blocks for the whole kernel (m114 pipe overlap),
// no serial tail. Wave-tile 64x48 (acc 48 regs) keeps 2 blocks reg-safe; LDS
// 3-ring x (A 8KB + B 12KB) = 60 KB -> 120 KB for 2 blocks.
// B staging = 768 chunks/tile: waves 0-3 issue 3 gld16/tile, waves 4-7 issue 2;
// counted wait is wave-uniform vmcnt(3)/vmcnt(2) (keeps stage(tau+2) in flight,
// drains tau+1; ring (tau+2)%3's prior reads completed before barrier(tau-1)).
// LDS chunk swizzle (validated, 0 conflicts): stored 16B chunk at row r, pos p
// holds global chunk (p - (r>>1)) & 3; fragment reads use pos ((quad+(l15>>1))&3).
// 192 does not divide 2048 -> q/k/v boundary resolved PER ni (16-col groups are
// uniform since 2048 % 16 == 0).
__global__ __launch_bounds__(512, 4) void gemm_qkv(const u16* __restrict__ A,
                                                   const u16* __restrict__ Bw,
                                                   u16* __restrict__ q3) {
  __shared__ __align__(16) u16 SA[12288];  // 3 rings x [128 rows][32 k] = 24 KiB
  __shared__ __align__(16) u16 SB[18432];  // 3 rings x [192 rows][32 k] = 36 KiB
  // bijective XCD swizzle: 1024 = 8 XCDs x 128; per XCD 4 n-panels x 32 m (B 3MB/L2)
  const int id = blockIdx.x;
  const int swz = (id & 7) * 128 + (id >> 3);
  const int by = swz & 31, bx = swz >> 5;
  const int m0 = by * 128, n0 = bx * 192;
  const int t = threadIdx.x, w = t >> 6, lane = t & 63;
  const int quad = lane >> 4, l15 = lane & 15;
  const int wm = w >> 2, wn = w & 3;  // 2 x 4 wave grid; per-wave C = 64 x 48
  // staging: thread t -> row rS = t>>2, LDS position pS = t&3;
  // source chunk cS = (pS - (rS>>1)) & 3; rows rS+128 (B 2nd half): same cS mod 4.
  const int rS = t >> 2, pS = t & 3;
  const int cS = (pS - (rS >> 1)) & 3;
  const size_t arowA = (size_t)(m0 + rS) * 2048 + cS * 8;
  const size_t arowB = (size_t)(n0 + rS) * 2048 + cS * 8;

  f32x4 acc[4][3] = {};  // 48 VGPR
  const int pq = ((quad + (l15 >> 1)) & 3) * 8;

#define STAGE(KT, RS_)                                   \
  {                                                      \
    const u16* ga_ = A + arowA + (size_t)(KT) * 32;      \
    gld16(ga_, SA + (RS_)*4096 + t * 8);                 \
    const u16* gb_ = Bw + arowB + (size_t)(KT) * 32;     \
    u16* lb_ = SB + (RS_)*6144 + t * 8;                  \
    gld16(gb_, lb_);                                     \
    if (w < 4) gld16(gb_ + (size_t)128 * 2048, lb_ + 4096); \
  }

// steady counted wait: waves 0-3 have 3 loads/tile outstanding per stage, 4-7 have 2
#define WAITQ                       \
  {                                 \
    if (w < 4) { WAIT_VM(3); }      \
    else       { WAIT_VM(2); }      \
  }

#define TILE(RC, RSS, TAU, DO_STAGE, WAIT)                                    \
  {                                                                           \
    const u16* Sa_ = SA + (RC)*4096;                                          \
    const u16* Sb_ = SB + (RC)*6144;                                          \
    if (DO_STAGE) STAGE((TAU) + 2, RSS);                                      \
    short8 af[4], bf[3];                                                      \
    _Pragma("unroll") for (int i = 0; i < 4; i++)                             \
        af[i] = *(const short8*)&Sa_[(wm * 64 + i * 16 + l15) * 32 + pq];     \
    _Pragma("unroll") for (int n = 0; n < 3; n++)                             \
        bf[n] = *(const short8*)&Sb_[(wn * 48 + n * 16 + l15) * 32 + pq];     \
    __builtin_amdgcn_s_setprio(1);                                            \
    _Pragma("unroll") for (int mi = 0; mi < 4; mi++)                          \
      _Pragma("unroll") for (int ni = 0; ni < 3; ni++)                        \
          acc[mi][ni] = mfma16(af[mi], bf[ni], acc[mi][ni]);                  \
    __builtin_amdgcn_s_setprio(0);                                            \
    WAIT;                                                                     \
    __builtin_amdgcn_s_barrier();                                             \
  }

  STAGE(0, 0);
  STAGE(1, 1);
  WAITQ;
  __builtin_amdgcn_s_barrier();

#pragma unroll 1
  for (int kt = 0; kt < 60; kt += 3) {
    TILE(0, 2, kt + 0, 1, WAITQ);
    TILE(1, 0, kt + 1, 1, WAITQ);
    TILE(2, 1, kt + 2, 1, WAITQ);
  }
  // tail: tau 60 stages 62 (ring 2), tau 61 stages 63 (ring 0); drain -> 0.
  TILE(0, 2, 60, 1, WAITQ);
  TILE(1, 0, 61, 1, WAITQ);
  TILE(2, 1, 62, 0, WAIT_VM(0));
  TILE(0, 2, 63, 0, (void)0);
#undef TILE
#undef WAITQ
#undef STAGE

  // ---- epilogue: scatter into q | k | vT (layouts match rope_k / attn_k) ----
  // C row = m0 + wm*64 + mi*16 + quad*4 + r ; C col = n0 + wn*48 + ni*16 + l15
  // which/head resolved per ni (16-col groups uniform: 2048 % 16 == 0).
  const int bb = m0 >> 11, tt0 = m0 & 2047;
#pragma unroll
  for (int ni = 0; ni < 3; ni++) {
    const int gc = n0 + wn * 48 + ni * 16 + l15;
    const int which = gc >> 11;  // 0=q 1=k 2=v, uniform across the wave per ni
    const int hh = (gc & 2047) >> 7, di = gc & 127;
    if (which == 2) {
      u16* vb = q3 + 16777216 + ((size_t)(bb * 16 + hh) * 128 + di) * 2048;
#pragma unroll
      for (int mi = 0; mi < 4; mi++) {
        const int tloc = tt0 + wm * 64 + mi * 16 + quad * 4;
        s16x4 st;
#pragma unroll
        for (int r = 0; r < 4; r++) st[r] = (short)f2bf(acc[mi][ni][r]);
        *(s16x4*)(vb + tloc) = st;  // 4 consecutive t -> 8B store
      }
    } else {
      const float sc = (which == 0) ? 0.1275174f : 1.0f;  // 1/sqrt(128)*log2(e)
      u16* qb = q3 + (size_t)which * 8388608 +
                ((size_t)(bb * 16 + hh) * 2048) * 128 + di;
#pragma unroll
      for (int mi = 0; mi < 4; mi++) {
        const int tloc = tt0 + wm * 64 + mi * 16 + quad * 4;
#pragma unroll
        for (int r = 0; r < 4; r++)
          qb[(size_t)(tloc + r) * 128] = f2bf(acc[mi][ni][r] * sc);
      }
    }
  }
}

// ---------------- BT GEMM (kept for the output projection), 32x32x16 MFMA --------
template <int EPI>
__global__ __launch_bounds__(256) void gemm_bt(const u16* __restrict__ A,
                                               const u16* __restrict__ B,
                                               int K, void* __restrict__ Cv, int N) {
  __shared__ __align__(16) u16 SMEM[8448];  // staging 16KB; EPI=1 epilogue f32[32][132]
  u16* As = SMEM;
  u16* Bs = SMEM + 4096;
  const int m0 = blockIdx.y * 128, n0 = blockIdx.x * 128;
  const int t = threadIdx.x, w = t >> 6, lane = t & 63;
  const int l31 = lane & 31, half = lane >> 5;
  const int rb = (w >> 1) * 64, cb = (w & 1) * 64;
  f32x16 acc[2][2] = {};
  const int rowS = w * 16 + (lane >> 2);                // staged row (0..63, +64 second)
  const int cS = ((lane & 3) - (rowS >> 1)) & 3;        // swizzled source chunk
  const u16* ag = A + (size_t)(m0 + rowS) * K + cS * 8;
  const u16* bg = B + (size_t)(n0 + rowS) * K + cS * 8;
  u16* al = As + w * 512 + lane * 8;  // lane-contiguous: base + lane*16B
  u16* bl = Bs + w * 512 + lane * 8;
  const size_t rowskip = (size_t)64 * K;
  const int p0 = ((0 * 2 + half + (l31 >> 1)) & 3) * 8;  // kh=0
  const int p1 = ((1 * 2 + half + (l31 >> 1)) & 3) * 8;  // kh=1
  for (int k0 = 0; k0 < K; k0 += 32) {
    __syncthreads();
    gld16(ag, al);
    gld16(ag + rowskip, al + 2048);
    gld16(bg, bl);
    gld16(bg + rowskip, bl + 2048);
    ag += 32;
    bg += 32;
    __syncthreads();
    short8 af[2][2], bfr[2][2];
#pragma unroll
    for (int mi = 0; mi < 2; mi++) {
      af[mi][0] = *(const short8*)&As[(rb + mi * 32 + l31) * 32 + p0];
      af[mi][1] = *(const short8*)&As[(rb + mi * 32 + l31) * 32 + p1];
    }
#pragma unroll
    for (int ni = 0; ni < 2; ni++) {
      bfr[ni][0] = *(const short8*)&Bs[(cb + ni * 32 + l31) * 32 + p0];
      bfr[ni][1] = *(const short8*)&Bs[(cb + ni * 32 + l31) * 32 + p1];
    }
#pragma unroll
    for (int kh = 0; kh < 2; kh++)
#pragma unroll
      for (int mi = 0; mi < 2; mi++)
#pragma unroll
        for (int ni = 0; ni < 2; ni++)
          acc[mi][ni] = mfma32(af[mi][kh], bfr[ni][kh], acc[mi][ni]);
  }

  if (EPI == 0) {
    const int which = n0 >> 11;
    const int hh = (n0 & 2047) >> 7;
    const int bb = m0 >> 11, tt0 = m0 & 2047;
    u16* q3 = (u16*)Cv;
    if (which == 2) {
      u16* vbase = q3 + 16777216 + ((size_t)(bb * 16 + hh) * 128) * 2048;
#pragma unroll
      for (int mi = 0; mi < 2; mi++)
#pragma unroll
        for (int ni = 0; ni < 2; ni++) {
          int di = cb + ni * 32 + l31;
          int trow = tt0 + rb + mi * 32 + half * 4;
#pragma unroll
          for (int rg2 = 0; rg2 < 4; rg2++) {
            s16x4 st;
#pragma unroll
            for (int j = 0; j < 4; j++) st[j] = (short)f2bf(acc[mi][ni][rg2 * 4 + j]);
            *(s16x4*)(vbase + (size_t)di * 2048 + trow + rg2 * 8) = st;
          }
        }
    } else {
      const float sc = (which == 0) ? 0.1275174f : 1.0f;
      u16* base = q3 + (size_t)which * 8388608 + ((size_t)(bb * 16 + hh) * 2048) * 128;
#pragma unroll
      for (int mi = 0; mi < 2; mi++)
#pragma unroll
        for (int ni = 0; ni < 2; ni++) {
          int di = cb + ni * 32 + l31;
          int trow = tt0 + rb + mi * 32 + half * 4;
#pragma unroll
          for (int reg = 0; reg < 16; reg++) {
            int tt = trow + (reg & 3) + 8 * (reg >> 2);
            base[(size_t)tt * 128 + di] = f2bf(acc[mi][ni][reg] * sc);
          }
        }
    }
  } else {
    float* Es = (float*)SMEM;  // [32][132]
    float* C = (float*)Cv;
#pragma unroll
    for (int r = 0; r < 4; r++) {
      __syncthreads();
      if ((w >> 1) == (r >> 1)) {
        const int mi = r & 1;
#pragma unroll
        for (int ni = 0; ni < 2; ni++) {
          int col = cb + ni * 32 + l31;
#pragma unroll
          for (int reg = 0; reg < 16; reg++) {
            int lrow = (reg & 3) + 8 * (reg >> 2) + half * 4;
            Es[lrow * 132 + col] = acc[mi][ni][reg];
          }
        }
      }
      __syncthreads();
#pragma unroll
      for (int it = 0; it < 4; it++) {
        int idx = it * 256 + t;
        int row = idx >> 5, ch = idx & 31;
        f32x4 vv = *(const f32x4*)&Es[row * 132 + ch * 4];
        *(f32x4*)&C[(size_t)(m0 + r * 32 + row) * N + n0 + ch * 4] = vv;
      }
    }
  }
}

// ---------------- RoPE in-place on q,k (heads 0..7 only) ----------------
__global__ __launch_bounds__(256) void rope_k(u16* __restrict__ q, u16* __restrict__ k,
                                              const float* __restrict__ cosT,
                                              const float* __restrict__ sinT) {
  int t = threadIdx.x;
  int row = blockIdx.x * 4 + (t >> 6);  // over (b, h<8, tpos)
  int i = t & 63;
  int b = row >> 14;
  int h = (row >> 11) & 7;
  int tp = row & 2047;
  size_t base = ((size_t)((b * 16 + h) * 2048 + tp)) * 128 + 2 * i;
  float c = cosT[tp * 64 + i], s = sinT[tp * 64 + i];
  {
    uint32_t u = *(uint32_t*)(q + base);
    float x0 = bf2f((u16)(u & 0xffff)), x1 = bf2f((u16)(u >> 16));
    float re = x0 * c - x1 * s, im = x0 * s + x1 * c;
    *(uint32_t*)(q + base) = (uint32_t)f2bf(re) | ((uint32_t)f2bf(im) << 16);
  }
  {
    uint32_t u = *(uint32_t*)(k + base);
    float x0 = bf2f((u16)(u & 0xffff)), x1 = bf2f((u16)(u >> 16));
    float re = x0 * c - x1 * s, im = x0 * s + x1 * c;
    *(uint32_t*)(k + base) = (uint32_t)f2bf(re) | ((uint32_t)f2bf(im) << 16);
  }
}

// ---------------- flash attention, S^T orientation, double-buffered K/V ----------
__global__ __launch_bounds__(256, 2) void attn_k(const u16* __restrict__ qh,
                                                 const u16* __restrict__ kh,
                                                 const u16* __restrict__ vTh,
                                                 u16* __restrict__ attno) {
  __shared__ __align__(16) u16 Ks[16384];  // 2 bufs x (64 keys x 128 d), XOR-swizzled
  __shared__ __align__(16) u16 Vt[16384];  // 2 bufs x (128 d x 64 keys), XOR-swizzled
  const int i = blockIdx.x;
  const int jj = i & 255, half = i >> 8;
  const int bh = jj >> 3, t8 = jj & 7;
  const int qt = half ? (15 - t8) : t8;
  const int q0 = qt * 128;
  const int t = threadIdx.x, w = t >> 6, lane = t & 63;
  const int quad = lane >> 4, l15 = lane & 15;
  const size_t bhoff = (size_t)bh * 262144;

  short8 qb[2][4];
  {
    const u16* qp = qh + bhoff + (size_t)(q0 + w * 32 + l15) * 128 + quad * 8;
#pragma unroll
    for (int qq = 0; qq < 2; qq++)
#pragma unroll
      for (int ks = 0; ks < 4; ks++)
        qb[qq][ks] = *(const short8*)(qp + qq * 2048 + ks * 32);
  }
  f32x4 of[2][8] = {};
  float mst[2] = {-1e30f, -1e30f}, lst[2] = {0.f, 0.f};
  const int nkt = 2 * qt + 2;
  const int wq0 = q0 + w * 32;

#define ASTAGE(KT, BUF)                                                        \
  {                                                                            \
    const int k0_ = (KT) * 64;                                                 \
    _Pragma("unroll") for (int it = 0; it < 4; it++) {                         \
      int L = it * 256 + t;                                                    \
      int key = L >> 4, c = L & 15;                                            \
      gld16(kh + bhoff + (size_t)(k0_ + key) * 128 + ((c ^ (key & 15)) * 8),   \
            Ks + (BUF)*8192 + (size_t)L * 8);                                  \
    }                                                                          \
    _Pragma("unroll") for (int it = 0; it < 4; it++) {                         \
      int L = it * 256 + t;                                                    \
      int d = L >> 3, c = L & 7;                                               \
      gld16(vTh + bhoff + (size_t)d * 2048 + k0_ + ((c ^ (d & 7)) * 8),        \
            Vt + (BUF)*8192 + (size_t)L * 8);                                  \
    }                                                                          \
  }

  ASTAGE(0, 0);
#pragma unroll 1
  for (int kt = 0; kt < nkt; kt++) {
    const int buf = kt & 1;
    const int k0 = kt * 64;
    __builtin_amdgcn_s_barrier();  // all waves done reading buf^1 (tile kt-1)
    if (kt + 1 < nkt) {
      ASTAGE(kt + 1, buf ^ 1);
      WAIT_VM(8);  // tile kt's 8 loads landed; kt+1's 8 stay in flight
    } else {
      WAIT_VM(0);
    }
    __builtin_amdgcn_s_barrier();  // tile kt visible to all waves
    if (k0 <= wq0 + 31) {
      const u16* Kb = Ks + buf * 8192;
      const u16* Vb = Vt + buf * 8192;
      f32x4 sacc[2][4];
#pragma unroll
      for (int qq = 0; qq < 2; qq++)
#pragma unroll
        for (int kk = 0; kk < 4; kk++) sacc[qq][kk] = (f32x4){0.f, 0.f, 0.f, 0.f};
#pragma unroll
      for (int kk = 0; kk < 4; kk++) {
        short8 kf[4];
#pragma unroll
        for (int ks = 0; ks < 4; ks++)
          kf[ks] = *(const short8*)&Kb[(kk * 16 + l15) * 128 + ((ks * 4 + quad) ^ l15) * 8];
        __builtin_amdgcn_s_setprio(1);
#pragma unroll
        for (int qq = 0; qq < 2; qq++)
#pragma unroll
          for (int ks = 0; ks < 4; ks++)
            sacc[qq][kk] = mfma16(kf[ks], qb[qq][ks], sacc[qq][kk]);
        __builtin_amdgcn_s_setprio(0);
      }
      const bool needmask = (k0 + 63 > wq0);
      s16x4 pf[2][4];
      float alpha[2];
#pragma unroll
      for (int qq = 0; qq < 2; qq++) {
        const int qg = wq0 + qq * 16 + l15;
        if (needmask) {
#pragma unroll
          for (int kk = 0; kk < 4; kk++)
#pragma unroll
            for (int rg = 0; rg < 4; rg++)
              if (k0 + kk * 16 + quad * 4 + rg > qg) sacc[qq][kk][rg] = -1e30f;
        }
        float pm = -1e30f;
#pragma unroll
        for (int kk = 0; kk < 4; kk++)
#pragma unroll
          for (int rg = 0; rg < 4; rg++) pm = fmaxf(pm, sacc[qq][kk][rg]);
        pm = fmaxf(pm, __shfl_xor(pm, 16));
        pm = fmaxf(pm, __shfl_xor(pm, 32));
        float mnew = fmaxf(mst[qq], pm);
        alpha[qq] = exp2a(mst[qq] - mnew);
        mst[qq] = mnew;
        float ps = 0.f;
#pragma unroll
        for (int kk = 0; kk < 4; kk++) {
          float e0 = exp2a(sacc[qq][kk][0] - mnew);
          float e1 = exp2a(sacc[qq][kk][1] - mnew);
          float e2 = exp2a(sacc[qq][kk][2] - mnew);
          float e3 = exp2a(sacc[qq][kk][3] - mnew);
          ps += (e0 + e1) + (e2 + e3);
          pf[qq][kk][0] = (short)f2bf(e0);
          pf[qq][kk][1] = (short)f2bf(e1);
          pf[qq][kk][2] = (short)f2bf(e2);
          pf[qq][kk][3] = (short)f2bf(e3);
        }
        ps += __shfl_xor(ps, 16);
        ps += __shfl_xor(ps, 32);
        lst[qq] = lst[qq] * alpha[qq] + ps;
      }
#pragma unroll
      for (int qq = 0; qq < 2; qq++) {
        if (!__all(alpha[qq] == 1.0f)) {
          float a = alpha[qq];
#pragma unroll
          for (int df = 0; df < 8; df++) of[qq][df] *= a;
        }
      }
#pragma unroll
      for (int df = 0; df < 8; df++) {
        s16x4 vf[4];
#pragma unroll
        for (int kk = 0; kk < 4; kk++)
          vf[kk] = *(const s16x4*)&Vb[(df * 16 + l15) * 64 +
                                      ((kk * 2 + (quad >> 1)) ^ (l15 & 7)) * 8 +
                                      (quad & 1) * 4];
        __builtin_amdgcn_s_setprio(1);
#pragma unroll
        for (int qq = 0; qq < 2; qq++)
#pragma unroll
          for (int kk = 0; kk < 4; kk++)
            of[qq][df] = mfma16k16(vf[kk], pf[qq][kk], of[qq][df]);
        __builtin_amdgcn_s_setprio(0);
      }
    }
  }
#undef ASTAGE
  const int b = bh >> 4, h = bh & 15;
#pragma unroll
  for (int qq = 0; qq < 2; qq++) {
    float linv = 1.0f / lst[qq];
    const size_t row = (size_t)(b * 2048 + q0 + w * 32 + qq * 16 + l15);
#pragma unroll
    for (int df = 0; df < 8; df++) {
      s16x4 o;
#pragma unroll
      for (int rg = 0; rg < 4; rg++) o[rg] = (short)f2bf(of[qq][df][rg] * linv);
      *(s16x4*)(attno + row * 2048 + h * 128 + df * 16 + quad * 4) = o;
    }
  }
}

extern "C" void kernel_launch(void* const* d_in, const int* in_sizes, int n_in,
                              void* d_out, int out_size, void* d_ws, size_t ws_size,
                              hipStream_t stream) {
  const float* x = (const float*)d_in[0];
  const float* Wqkv = (const float*)d_in[1];
  const float* Wout = (const float*)d_in[2];
  const float* cosT = (const float*)d_in[3];
  const float* sinT = (const float*)d_in[4];
  float* out = (float*)d_out;
  char* ws = (char*)d_ws;
  // workspace (96 MiB), lifetime-based reuse:
  //   [0,        50331648)  qkvh: q | k | vT (vT = per-head transposed v)
  //   [50331648, 58720256)  woutb (persists to gemm2)
  //   [58720256, 75497472)  xb (dead after gemm1)
  //   [75497472,100663296)  wqkvb (dead after gemm1) -> reused as attno
  u16* qkvh = (u16*)(ws + 0);
  u16* woutb = (u16*)(ws + 50331648);
  u16* xb = (u16*)(ws + 58720256);
  u16* wqkvb = (u16*)(ws + 75497472);
  u16* attno = wqkvb;

  cvt_all<<<12288, 256, 0, stream>>>(x, Wqkv, Wout, xb, wqkvb, woutb);
  gemm_qkv<<<1024, 512, 0, stream>>>(xb, wqkvb, qkvh);
  rope_k<<<8192, 256, 0, stream>>>(qkvh, qkvh + 8388608, cosT, sinT);
  attn_k<<<512, 256, 0, stream>>>(qkvh, qkvh + 8388608, qkvh + 16777216, attno);
  gemm_bt<1><<<dim3(16, 32), 256, 0, stream>>>(attno, woutb, 2048, (void*)out, 2048);
}

// Round 8
// 386.455 us; speedup vs baseline: 1.0577x; 1.0101x over previous
//
#include <hip/hip_runtime.h>
#include <stdint.h>

typedef unsigned short u16;
typedef __attribute__((ext_vector_type(8))) short short8;
typedef __attribute__((ext_vector_type(4))) short s16x4;
typedef __attribute__((ext_vector_type(4))) float f32x4;
typedef __attribute__((ext_vector_type(16))) float f32x16;

__device__ __forceinline__ u16 f2bf(float f) {
  uint32_t x = __float_as_uint(f);
  x += 0x7fff + ((x >> 16) & 1);
  return (u16)(x >> 16);
}
__device__ __forceinline__ float bf2f(u16 u) {
  return __uint_as_float(((uint32_t)u) << 16);
}
__device__ __forceinline__ f32x4 mfma16(short8 a, short8 b, f32x4 c) {
  return __builtin_amdgcn_mfma_f32_16x16x32_bf16(a, b, c, 0, 0, 0);
}
__device__ __forceinline__ f32x4 mfma16k16(s16x4 a, s16x4 b, f32x4 c) {
  return __builtin_amdgcn_mfma_f32_16x16x16bf16_1k(a, b, c, 0, 0, 0);
}
__device__ __forceinline__ void gld16(const u16* g, u16* l) {
  __builtin_amdgcn_global_load_lds(
      (const __attribute__((address_space(1))) unsigned int*)g,
      (__attribute__((address_space(3))) unsigned int*)l, 16, 0, 0);
}
__device__ __forceinline__ float exp2a(float x) {  // raw v_exp_f32 (2^x)
  float r;
  asm("v_exp_f32 %0, %1" : "=v"(r) : "v"(x));
  return r;
}

#define WAIT_VM(n) asm volatile("s_waitcnt vmcnt(" #n ")" ::: "memory")

// ---------------- fused fp32 -> bf16 conversion (x | Wqkv | Wout) ----------------
__global__ __launch_bounds__(256) void cvt_all(const float* __restrict__ x,
                                               const float* __restrict__ wqkv,
                                               const float* __restrict__ wout,
                                               u16* __restrict__ xb,
                                               u16* __restrict__ wqkvb,
                                               u16* __restrict__ woutb) {
  long i = ((long)blockIdx.x * 256 + threadIdx.x) * 8;
  const float* s;
  u16* d;
  long off;
  if (i < 8388608) {
    s = x; d = xb; off = i;
  } else if (i < 20971520) {
    s = wqkv; d = wqkvb; off = i - 8388608;
  } else {
    s = wout; d = woutb; off = i - 20971520;
  }
  f32x4 a = *(const f32x4*)(s + off);
  f32x4 b = *(const f32x4*)(s + off + 4);
  short8 o;
#pragma unroll
  for (int j = 0; j < 4; j++) {
    o[j] = (short)f2bf(a[j]);
    o[j + 4] = (short)f2bf(b[j]);
  }
  *(short8*)(d + off) = o;
}

// ---------------- QKV GEMM: 128x192 tile, 8 waves, BK=32, 3-ring LDS ----------------
// (frozen; round-7 measured 129.8 us, 0 bank conflicts, occupancy 41%, FETCH 143GB)
__global__ __launch_bounds__(512, 4) void gemm_qkv(const u16* __restrict__ A,
                                                   const u16* __restrict__ Bw,
                                                   u16* __restrict__ q3) {
  __shared__ __align__(16) u16 SA[12288];  // 3 rings x [128 rows][32 k] = 24 KiB
  __shared__ __align__(16) u16 SB[18432];  // 3 rings x [192 rows][32 k] = 36 KiB
  const int id = blockIdx.x;
  const int swz = (id & 7) * 128 + (id >> 3);
  const int by = swz & 31, bx = swz >> 5;
  const int m0 = by * 128, n0 = bx * 192;
  const int t = threadIdx.x, w = t >> 6, lane = t & 63;
  const int quad = lane >> 4, l15 = lane & 15;
  const int wm = w >> 2, wn = w & 3;  // 2 x 4 wave grid; per-wave C = 64 x 48
  const int rS = t >> 2, pS = t & 3;
  const int cS = (pS - (rS >> 1)) & 3;
  const size_t arowA = (size_t)(m0 + rS) * 2048 + cS * 8;
  const size_t arowB = (size_t)(n0 + rS) * 2048 + cS * 8;

  f32x4 acc[4][3] = {};  // 48 VGPR
  const int pq = ((quad + (l15 >> 1)) & 3) * 8;

#define STAGE(KT, RS_)                                   \
  {                                                      \
    const u16* ga_ = A + arowA + (size_t)(KT) * 32;      \
    gld16(ga_, SA + (RS_)*4096 + t * 8);                 \
    const u16* gb_ = Bw + arowB + (size_t)(KT) * 32;     \
    u16* lb_ = SB + (RS_)*6144 + t * 8;                  \
    gld16(gb_, lb_);                                     \
    if (w < 4) gld16(gb_ + (size_t)128 * 2048, lb_ + 4096); \
  }

#define WAITQ                       \
  {                                 \
    if (w < 4) { WAIT_VM(3); }      \
    else       { WAIT_VM(2); }      \
  }

#define TILE(RC, RSS, TAU, DO_STAGE, WAIT)                                    \
  {                                                                           \
    const u16* Sa_ = SA + (RC)*4096;                                          \
    const u16* Sb_ = SB + (RC)*6144;                                          \
    if (DO_STAGE) STAGE((TAU) + 2, RSS);                                      \
    short8 af[4], bf[3];                                                      \
    _Pragma("unroll") for (int i = 0; i < 4; i++)                             \
        af[i] = *(const short8*)&Sa_[(wm * 64 + i * 16 + l15) * 32 + pq];     \
    _Pragma("unroll") for (int n = 0; n < 3; n++)                             \
        bf[n] = *(const short8*)&Sb_[(wn * 48 + n * 16 + l15) * 32 + pq];     \
    __builtin_amdgcn_s_setprio(1);                                            \
    _Pragma("unroll") for (int mi = 0; mi < 4; mi++)                          \
      _Pragma("unroll") for (int ni = 0; ni < 3; ni++)                        \
          acc[mi][ni] = mfma16(af[mi], bf[ni], acc[mi][ni]);                  \
    __builtin_amdgcn_s_setprio(0);                                            \
    WAIT;                                                                     \
    __builtin_amdgcn_s_barrier();                                             \
  }

  STAGE(0, 0);
  STAGE(1, 1);
  WAITQ;
  __builtin_amdgcn_s_barrier();

#pragma unroll 1
  for (int kt = 0; kt < 60; kt += 3) {
    TILE(0, 2, kt + 0, 1, WAITQ);
    TILE(1, 0, kt + 1, 1, WAITQ);
    TILE(2, 1, kt + 2, 1, WAITQ);
  }
  TILE(0, 2, 60, 1, WAITQ);
  TILE(1, 0, 61, 1, WAITQ);
  TILE(2, 1, 62, 0, WAIT_VM(0));
  TILE(0, 2, 63, 0, (void)0);
#undef TILE
#undef WAITQ
#undef STAGE

  // ---- epilogue: scatter into q | k | vT (layouts match rope_k / attn_k) ----
  const int bb = m0 >> 11, tt0 = m0 & 2047;
#pragma unroll
  for (int ni = 0; ni < 3; ni++) {
    const int gc = n0 + wn * 48 + ni * 16 + l15;
    const int which = gc >> 11;  // 0=q 1=k 2=v, uniform across the wave per ni
    const int hh = (gc & 2047) >> 7, di = gc & 127;
    if (which == 2) {
      u16* vb = q3 + 16777216 + ((size_t)(bb * 16 + hh) * 128 + di) * 2048;
#pragma unroll
      for (int mi = 0; mi < 4; mi++) {
        const int tloc = tt0 + wm * 64 + mi * 16 + quad * 4;
        s16x4 st;
#pragma unroll
        for (int r = 0; r < 4; r++) st[r] = (short)f2bf(acc[mi][ni][r]);
        *(s16x4*)(vb + tloc) = st;  // 4 consecutive t -> 8B store
      }
    } else {
      const float sc = (which == 0) ? 0.1275174f : 1.0f;  // 1/sqrt(128)*log2(e)
      u16* qb = q3 + (size_t)which * 8388608 +
                ((size_t)(bb * 16 + hh) * 2048) * 128 + di;
#pragma unroll
      for (int mi = 0; mi < 4; mi++) {
        const int tloc = tt0 + wm * 64 + mi * 16 + quad * 4;
#pragma unroll
        for (int r = 0; r < 4; r++)
          qb[(size_t)(tloc + r) * 128] = f2bf(acc[mi][ni][r] * sc);
      }
    }
  }
}

// ---------------- output projection GEMM: 128x128 tile, 8 waves, BK=32, 3-ring ----
// Round-8: replaces the round-0-era gemm_bt<1> with the VALIDATED gemm_qkv recipe
// (rounds 5-7: 512 thr, 3-ring counted-vmcnt, chunk swizzle, 2 blocks/CU).
// C(4096x2048, fp32) = attno(4096x2048) * woutb(2048x2048)^T, K = 2048 -> 64 tiles.
// Grid 32x16 = 512 blocks = exactly 2/CU x 1 round. Wave-tile 64x32 (acc 32 VGPR).
// LDS 3 rings x (A 8KB + B 8KB) = 48 KB -> 96 KB for 2 blocks. Staging = exactly
// one gld16 per thread per operand (512 chunks each); steady wait vmcnt(2) keeps
// stage(tau+2)'s 2 loads in flight. Same swizzle: chunk at row r pos p holds global
// chunk (p-(r>>1))&3; frag reads at pos ((quad+(l15>>1))&3).
// fp32 epilogue via LDS bounce (reuse SA, f32[32][132]) -> dwordx4 stores.
__global__ __launch_bounds__(512, 4) void gemm_out(const u16* __restrict__ A,
                                                   const u16* __restrict__ Bw,
                                                   float* __restrict__ C) {
  __shared__ __align__(16) u16 SA[12288];  // 3 rings x [128][32] = 24 KiB
  __shared__ __align__(16) u16 SB[12288];  // 3 rings x [128][32] = 24 KiB
  // XCD swizzle: 512 = 8 XCDs x 64
  const int id = blockIdx.x;
  const int swz = (id & 7) * 64 + (id >> 3);
  const int by = swz & 31, bx = swz >> 5;
  const int m0 = by * 128, n0 = bx * 128;
  const int t = threadIdx.x, w = t >> 6, lane = t & 63;
  const int quad = lane >> 4, l15 = lane & 15;
  const int wm = w >> 2, wn = w & 3;  // 2 x 4 wave grid; per-wave C = 64 x 32
  const int rS = t >> 2, pS = t & 3;
  const int cS = (pS - (rS >> 1)) & 3;
  const size_t arowA = (size_t)(m0 + rS) * 2048 + cS * 8;
  const size_t arowB = (size_t)(n0 + rS) * 2048 + cS * 8;

  f32x4 acc[4][2] = {};  // 32 VGPR
  const int pq = ((quad + (l15 >> 1)) & 3) * 8;

#define STAGE(KT, RS_)                                   \
  {                                                      \
    gld16(A + arowA + (size_t)(KT) * 32, SA + (RS_)*4096 + t * 8); \
    gld16(Bw + arowB + (size_t)(KT) * 32, SB + (RS_)*4096 + t * 8); \
  }

#define TILE(RC, RSS, TAU, DO_STAGE, WAIT)                                    \
  {                                                                           \
    const u16* Sa_ = SA + (RC)*4096;                                          \
    const u16* Sb_ = SB + (RC)*4096;                                          \
    if (DO_STAGE) STAGE((TAU) + 2, RSS);                                      \
    short8 af[4], bf[2];                                                      \
    _Pragma("unroll") for (int i = 0; i < 4; i++)                             \
        af[i] = *(const short8*)&Sa_[(wm * 64 + i * 16 + l15) * 32 + pq];     \
    _Pragma("unroll") for (int n = 0; n < 2; n++)                             \
        bf[n] = *(const short8*)&Sb_[(wn * 32 + n * 16 + l15) * 32 + pq];     \
    __builtin_amdgcn_s_setprio(1);                                            \
    _Pragma("unroll") for (int mi = 0; mi < 4; mi++)                          \
      _Pragma("unroll") for (int ni = 0; ni < 2; ni++)                        \
          acc[mi][ni] = mfma16(af[mi], bf[ni], acc[mi][ni]);                  \
    __builtin_amdgcn_s_setprio(0);                                            \
    WAIT;                                                                     \
    __builtin_amdgcn_s_barrier();                                             \
  }

  STAGE(0, 0);
  STAGE(1, 1);
  WAIT_VM(2);
  __builtin_amdgcn_s_barrier();

#pragma unroll 1
  for (int kt = 0; kt < 60; kt += 3) {
    TILE(0, 2, kt + 0, 1, WAIT_VM(2));
    TILE(1, 0, kt + 1, 1, WAIT_VM(2));
    TILE(2, 1, kt + 2, 1, WAIT_VM(2));
  }
  TILE(0, 2, 60, 1, WAIT_VM(2));
  TILE(1, 0, 61, 1, WAIT_VM(2));
  TILE(2, 1, 62, 0, WAIT_VM(0));
  TILE(0, 2, 63, 0, (void)0);
#undef TILE
#undef STAGE

  // ---- fp32 epilogue: LDS bounce (rows in 4 groups of 32) -> dwordx4 stores ----
  float* Es = (float*)SA;  // [32][132] = 16.9 KB <= 24 KB
#pragma unroll
  for (int r = 0; r < 4; r++) {
    __syncthreads();
    if (wm == (r >> 1)) {
      const int mib = (r & 1) * 2;
#pragma unroll
      for (int ni = 0; ni < 2; ni++) {
        const int col = wn * 32 + ni * 16 + l15;
#pragma unroll
        for (int mo = 0; mo < 2; mo++)
#pragma unroll
          for (int rg = 0; rg < 4; rg++) {
            const int lrow = mo * 16 + quad * 4 + rg;
            Es[lrow * 132 + col] = acc[mib + mo][ni][rg];
          }
      }
    }
    __syncthreads();
#pragma unroll
    for (int it = 0; it < 2; it++) {
      const int idx = it * 512 + t;
      const int row = idx >> 5, ch = idx & 31;
      f32x4 vv = *(const f32x4*)&Es[row * 132 + ch * 4];
      *(f32x4*)&C[(size_t)(m0 + r * 32 + row) * 2048 + n0 + ch * 4] = vv;
    }
  }
}

// ---------------- RoPE in-place on q,k (heads 0..7 only) ----------------
__global__ __launch_bounds__(256) void rope_k(u16* __restrict__ q, u16* __restrict__ k,
                                              const float* __restrict__ cosT,
                                              const float* __restrict__ sinT) {
  int t = threadIdx.x;
  int row = blockIdx.x * 4 + (t >> 6);  // over (b, h<8, tpos)
  int i = t & 63;
  int b = row >> 14;
  int h = (row >> 11) & 7;
  int tp = row & 2047;
  size_t base = ((size_t)((b * 16 + h) * 2048 + tp)) * 128 + 2 * i;
  float c = cosT[tp * 64 + i], s = sinT[tp * 64 + i];
  {
    uint32_t u = *(uint32_t*)(q + base);
    float x0 = bf2f((u16)(u & 0xffff)), x1 = bf2f((u16)(u >> 16));
    float re = x0 * c - x1 * s, im = x0 * s + x1 * c;
    *(uint32_t*)(q + base) = (uint32_t)f2bf(re) | ((uint32_t)f2bf(im) << 16);
  }
  {
    uint32_t u = *(uint32_t*)(k + base);
    float x0 = bf2f((u16)(u & 0xffff)), x1 = bf2f((u16)(u >> 16));
    float re = x0 * c - x1 * s, im = x0 * s + x1 * c;
    *(uint32_t*)(k + base) = (uint32_t)f2bf(re) | ((uint32_t)f2bf(im) << 16);
  }
}

// ---------------- flash attention, S^T orientation, double-buffered K/V ----------
__global__ __launch_bounds__(256, 2) void attn_k(const u16* __restrict__ qh,
                                                 const u16* __restrict__ kh,
                                                 const u16* __restrict__ vTh,
                                                 u16* __restrict__ attno) {
  __shared__ __align__(16) u16 Ks[16384];  // 2 bufs x (64 keys x 128 d), XOR-swizzled
  __shared__ __align__(16) u16 Vt[16384];  // 2 bufs x (128 d x 64 keys), XOR-swizzled
  const int i = blockIdx.x;
  const int jj = i & 255, half = i >> 8;
  const int bh = jj >> 3, t8 = jj & 7;
  const int qt = half ? (15 - t8) : t8;
  const int q0 = qt * 128;
  const int t = threadIdx.x, w = t >> 6, lane = t & 63;
  const int quad = lane >> 4, l15 = lane & 15;
  const size_t bhoff = (size_t)bh * 262144;

  short8 qb[2][4];
  {
    const u16* qp = qh + bhoff + (size_t)(q0 + w * 32 + l15) * 128 + quad * 8;
#pragma unroll
    for (int qq = 0; qq < 2; qq++)
#pragma unroll
      for (int ks = 0; ks < 4; ks++)
        qb[qq][ks] = *(const short8*)(qp + qq * 2048 + ks * 32);
  }
  f32x4 of[2][8] = {};
  float mst[2] = {-1e30f, -1e30f}, lst[2] = {0.f, 0.f};
  const int nkt = 2 * qt + 2;
  const int wq0 = q0 + w * 32;

#define ASTAGE(KT, BUF)                                                        \
  {                                                                            \
    const int k0_ = (KT) * 64;                                                 \
    _Pragma("unroll") for (int it = 0; it < 4; it++) {                         \
      int L = it * 256 + t;                                                    \
      int key = L >> 4, c = L & 15;                                            \
      gld16(kh + bhoff + (size_t)(k0_ + key) * 128 + ((c ^ (key & 15)) * 8),   \
            Ks + (BUF)*8192 + (size_t)L * 8);                                  \
    }                                                                          \
    _Pragma("unroll") for (int it = 0; it < 4; it++) {                         \
      int L = it * 256 + t;                                                    \
      int d = L >> 3, c = L & 7;                                               \
      gld16(vTh + bhoff + (size_t)d * 2048 + k0_ + ((c ^ (d & 7)) * 8),        \
            Vt + (BUF)*8192 + (size_t)L * 8);                                  \
    }                                                                          \
  }

  ASTAGE(0, 0);
#pragma unroll 1
  for (int kt = 0; kt < nkt; kt++) {
    const int buf = kt & 1;
    const int k0 = kt * 64;
    __builtin_amdgcn_s_barrier();  // all waves done reading buf^1 (tile kt-1)
    if (kt + 1 < nkt) {
      ASTAGE(kt + 1, buf ^ 1);
      WAIT_VM(8);  // tile kt's 8 loads landed; kt+1's 8 stay in flight
    } else {
      WAIT_VM(0);
    }
    __builtin_amdgcn_s_barrier();  // tile kt visible to all waves
    if (k0 <= wq0 + 31) {
      const u16* Kb = Ks + buf * 8192;
      const u16* Vb = Vt + buf * 8192;
      f32x4 sacc[2][4];
#pragma unroll
      for (int qq = 0; qq < 2; qq++)
#pragma unroll
        for (int kk = 0; kk < 4; kk++) sacc[qq][kk] = (f32x4){0.f, 0.f, 0.f, 0.f};
#pragma unroll
      for (int kk = 0; kk < 4; kk++) {
        short8 kf[4];
#pragma unroll
        for (int ks = 0; ks < 4; ks++)
          kf[ks] = *(const short8*)&Kb[(kk * 16 + l15) * 128 + ((ks * 4 + quad) ^ l15) * 8];
        __builtin_amdgcn_s_setprio(1);
#pragma unroll
        for (int qq = 0; qq < 2; qq++)
#pragma unroll
          for (int ks = 0; ks < 4; ks++)
            sacc[qq][kk] = mfma16(kf[ks], qb[qq][ks], sacc[qq][kk]);
        __builtin_amdgcn_s_setprio(0);
      }
      const bool needmask = (k0 + 63 > wq0);
      s16x4 pf[2][4];
      float alpha[2];
#pragma unroll
      for (int qq = 0; qq < 2; qq++) {
        const int qg = wq0 + qq * 16 + l15;
        if (needmask) {
#pragma unroll
          for (int kk = 0; kk < 4; kk++)
#pragma unroll
            for (int rg = 0; rg < 4; rg++)
              if (k0 + kk * 16 + quad * 4 + rg > qg) sacc[qq][kk][rg] = -1e30f;
        }
        float pm = -1e30f;
#pragma unroll
        for (int kk = 0; kk < 4; kk++)
#pragma unroll
          for (int rg = 0; rg < 4; rg++) pm = fmaxf(pm, sacc[qq][kk][rg]);
        pm = fmaxf(pm, __shfl_xor(pm, 16));
        pm = fmaxf(pm, __shfl_xor(pm, 32));
        float mnew = fmaxf(mst[qq], pm);
        alpha[qq] = exp2a(mst[qq] - mnew);
        mst[qq] = mnew;
        float ps = 0.f;
#pragma unroll
        for (int kk = 0; kk < 4; kk++) {
          float e0 = exp2a(sacc[qq][kk][0] - mnew);
          float e1 = exp2a(sacc[qq][kk][1] - mnew);
          float e2 = exp2a(sacc[qq][kk][2] - mnew);
          float e3 = exp2a(sacc[qq][kk][3] - mnew);
          ps += (e0 + e1) + (e2 + e3);
          pf[qq][kk][0] = (short)f2bf(e0);
          pf[qq][kk][1] = (short)f2bf(e1);
          pf[qq][kk][2] = (short)f2bf(e2);
          pf[qq][kk][3] = (short)f2bf(e3);
        }
        ps += __shfl_xor(ps, 16);
        ps += __shfl_xor(ps, 32);
        lst[qq] = lst[qq] * alpha[qq] + ps;
      }
#pragma unroll
      for (int qq = 0; qq < 2; qq++) {
        if (!__all(alpha[qq] == 1.0f)) {
          float a = alpha[qq];
#pragma unroll
          for (int df = 0; df < 8; df++) of[qq][df] *= a;
        }
      }
#pragma unroll
      for (int df = 0; df < 8; df++) {
        s16x4 vf[4];
#pragma unroll
        for (int kk = 0; kk < 4; kk++)
          vf[kk] = *(const s16x4*)&Vb[(df * 16 + l15) * 64 +
                                      ((kk * 2 + (quad >> 1)) ^ (l15 & 7)) * 8 +
                                      (quad & 1) * 4];
        __builtin_amdgcn_s_setprio(1);
#pragma unroll
        for (int qq = 0; qq < 2; qq++)
#pragma unroll
          for (int kk = 0; kk < 4; kk++)
            of[qq][df] = mfma16k16(vf[kk], pf[qq][kk], of[qq][df]);
        __builtin_amdgcn_s_setprio(0);
      }
    }
  }
#undef ASTAGE
  const int b = bh >> 4, h = bh & 15;
#pragma unroll
  for (int qq = 0; qq < 2; qq++) {
    float linv = 1.0f / lst[qq];
    const size_t row = (size_t)(b * 2048 + q0 + w * 32 + qq * 16 + l15);
#pragma unroll
    for (int df = 0; df < 8; df++) {
      s16x4 o;
#pragma unroll
      for (int rg = 0; rg < 4; rg++) o[rg] = (short)f2bf(of[qq][df][rg] * linv);
      *(s16x4*)(attno + row * 2048 + h * 128 + df * 16 + quad * 4) = o;
    }
  }
}

extern "C" void kernel_launch(void* const* d_in, const int* in_sizes, int n_in,
                              void* d_out, int out_size, void* d_ws, size_t ws_size,
                              hipStream_t stream) {
  const float* x = (const float*)d_in[0];
  const float* Wqkv = (const float*)d_in[1];
  const float* Wout = (const float*)d_in[2];
  const float* cosT = (const float*)d_in[3];
  const float* sinT = (const float*)d_in[4];
  float* out = (float*)d_out;
  char* ws = (char*)d_ws;
  // workspace (96 MiB), lifetime-based reuse:
  //   [0,        50331648)  qkvh: q | k | vT (vT = per-head transposed v)
  //   [50331648, 58720256)  woutb (persists to gemm_out)
  //   [58720256, 75497472)  xb (dead after gemm1)
  //   [75497472,100663296)  wqkvb (dead after gemm1) -> reused as attno
  u16* qkvh = (u16*)(ws + 0);
  u16* woutb = (u16*)(ws + 50331648);
  u16* xb = (u16*)(ws + 58720256);
  u16* wqkvb = (u16*)(ws + 75497472);
  u16* attno = wqkvb;

  cvt_all<<<12288, 256, 0, stream>>>(x, Wqkv, Wout, xb, wqkvb, woutb);
  gemm_qkv<<<1024, 512, 0, stream>>>(xb, wqkvb, qkvh);
  rope_k<<<8192, 256, 0, stream>>>(qkvh, qkvh + 8388608, cosT, sinT);
  attn_k<<<512, 256, 0, stream>>>(qkvh, qkvh + 8388608, qkvh + 16777216, attno);
  gemm_out<<<512, 512, 0, stream>>>(attno, woutb, out);
}